// Round 13
// baseline (284.466 us; speedup 1.0000x reference)
//
#include <hip/hip_runtime.h>
#include <cstdint>

#define NN 100000
#define NE 1600000
#define FI 602
#define DD 32
#define CC 41
#define BN_EPS 1e-5f
#define KSTEPS 19                 // 19*32 = 608 >= 602 (k-padded with zeros)

// single-pass bucketed CSR build
#define NPB 256                   // nodes per bucket (dst >> 8)
#define NB 391                    // ceil(NN/NPB)
#define BST 4608                  // fixed bucket stride (mean 4096, sigma 64 -> 8-sigma margin)
#define EPT 13                    // edges per thread in scatter
#define SCB 481                   // ceil(NE / (256*EPT))

typedef __attribute__((ext_vector_type(8))) short bf16x8;
typedef __attribute__((ext_vector_type(4))) float f32x4;

__device__ __forceinline__ void atomAdd(float* p, float v) {
#ifdef __HIP_PLATFORM_AMD__
  unsafeAtomicAdd(p, v);
#else
  atomicAdd(p, v);
#endif
}

// round-to-nearest-even f32 -> bf16 bits
__device__ __forceinline__ unsigned short f2b(float f) {
  unsigned u = __float_as_uint(f);
  unsigned r = (u + 0x7fffu + ((u >> 16) & 1u)) >> 16;
  return (unsigned short)r;
}
__device__ __forceinline__ float blo(unsigned u) { return __uint_as_float(u << 16); }
__device__ __forceinline__ float bhi(unsigned u) { return __uint_as_float(u & 0xffff0000u); }

// ---------------- K0: M = lin1_w @ nn1_w1 as MFMA B-fragments (single RNE bf16) ; cvec ; zero stats
__global__ __launch_bounds__(256) void k0_prep(
    const float* __restrict__ lin1_w, const float* __restrict__ lin1_b,
    const float* __restrict__ nn1_w1,
    unsigned short* __restrict__ Bh,
    float* __restrict__ cvec,
    float* __restrict__ stats1, float* __restrict__ stats2) {
  int o = blockIdx.x * 256 + threadIdx.x;   // over 608*32
  if (o < KSTEPS * 32 * 32) {
    int k = o >> 5, j = o & 31;
    float s = 0.f;
    if (k < FI) {
      #pragma unroll 4
      for (int c = 0; c < 2 * DD; ++c) s = fmaf(lin1_w[k * (2 * DD) + c], nn1_w1[c * DD + j], s);
    }
    int st = k >> 5, kk = k & 31, g = kk >> 3, jj = kk & 7;
    int h = j >> 4, lane = g * 16 + (j & 15);
    int idx = ((st * 2 + h) * 64 + lane) * 8 + jj;
    Bh[idx] = f2b(s);
  }
  if (blockIdx.x == 0) {
    int t = threadIdx.x;
    if (t < DD) {
      float s = 0.f;
      for (int c = 0; c < 2 * DD; ++c) s = fmaf(lin1_b[c], nn1_w1[c * DD + t], s);
      cvec[t] = s;
    }
    if (t >= 128 && t < 192) stats1[t - 128] = 0.f;
    if (t >= 192) stats2[t - 192] = 0.f;
  }
}

// ---------------- single-pass scatter into fixed-stride buckets ----------------
__global__ __launch_bounds__(256) void kb_scatter(const int* __restrict__ ei,
                                                  int* __restrict__ bcursor,
                                                  int* __restrict__ tsrc,
                                                  unsigned char* __restrict__ tdst) {
  __shared__ int cnt[NB];
  __shared__ int wbase[NB];
  const int t = threadIdx.x;
  for (int i = t; i < NB; i += 256) cnt[i] = 0;
  __syncthreads();
  const int base = blockIdx.x * (256 * EPT);
  int s[EPT], d[EPT];
  #pragma unroll
  for (int i = 0; i < EPT; ++i) {
    int e = base + i * 256 + t;
    if (e < NE) {
      s[i] = ei[e];
      d[i] = ei[NE + e];
      atomicAdd(&cnt[d[i] >> 8], 1);
    } else {
      s[i] = -1; d[i] = -1;
    }
  }
  __syncthreads();
  for (int i = t; i < NB; i += 256) wbase[i] = atomicAdd(&bcursor[i], cnt[i]);
  __syncthreads();
  #pragma unroll
  for (int i = 0; i < EPT; ++i) {
    if (d[i] >= 0) {
      int bk = d[i] >> 8;
      int p = atomicAdd(&wbase[bk], 1);
      int gp = bk * BST + p;
      tsrc[gp] = s[i];
      tdst[gp] = (unsigned char)(d[i] & (NPB - 1));
    }
  }
}

// ---------------- per-bucket fine sort: rs/re + compact srcidx (bucket-strided CSR)
__global__ __launch_bounds__(256) void kb_fine(const int* __restrict__ bcursor,
                                               const int* __restrict__ tsrc,
                                               const unsigned char* __restrict__ tdst,
                                               int* __restrict__ rs, int* __restrict__ re,
                                               int* __restrict__ srcidx) {
  __shared__ int deg[NPB];
  __shared__ int cur[NPB];
  __shared__ int woff[4];
  const int b = blockIdx.x, t = threadIdx.x;
  const int beg = b * BST;
  const int end = beg + bcursor[b];
  deg[t] = 0;
  __syncthreads();
  for (int i = beg + t; i < end; i += 256) atomicAdd(&deg[tdst[i]], 1);
  __syncthreads();
  int v = deg[t];
  int lane = t & 63, wave = t >> 6;
  int inc = v;
  #pragma unroll
  for (int off = 1; off < 64; off <<= 1) {
    int u = __shfl_up(inc, off);
    if (lane >= off) inc += u;
  }
  if (lane == 63) woff[wave] = inc;
  __syncthreads();
  int wadd = 0;
  for (int w = 0; w < wave; ++w) wadd += woff[w];
  int excl = wadd + inc - v;
  int gnode = b * NPB + t;
  if (gnode < NN) {
    rs[gnode] = beg + excl;
    re[gnode] = beg + excl + v;
  }
  cur[t] = beg + excl;
  __syncthreads();
  for (int i = beg + t; i < end; i += 256) {
    int p = atomicAdd(&cur[tdst[i]], 1);
    srcidx[p] = tsrc[i];
  }
}

// ---------------- K1 v7 (MFMA): zb = bf16(x @ M + cvec)
__global__ __launch_bounds__(256) void k1_mfma(
    const float* __restrict__ x,
    const unsigned short* __restrict__ Bh,
    const float* __restrict__ cvec, unsigned short* __restrict__ zb) {
  const int lane = threadIdx.x & 63;
  const int wid = (blockIdx.x * 256 + threadIdx.x) >> 6;
  const int row0 = wid * 16;
  if (row0 >= NN) return;
  const int g = lane >> 4;
  const int r = row0 + (lane & 15);
  const float* __restrict__ xr = x + (size_t)r * FI + g * 8;
  f32x4 acc0 = {0.f, 0.f, 0.f, 0.f};
  f32x4 acc1 = {0.f, 0.f, 0.f, 0.f};

  float4 a0 = *(const float4*)&xr[0];
  float4 b0 = *(const float4*)&xr[4];
  float4 a1 = *(const float4*)&xr[32];
  float4 b1 = *(const float4*)&xr[36];
  bf16x8 f0c = *(const bf16x8*)&Bh[(size_t)lane * 8];
  bf16x8 f1c = *(const bf16x8*)&Bh[(size_t)lane * 8 + 512];

  #pragma unroll
  for (int s = 0; s < KSTEPS; ++s) {
    float4 ca = a0, cb = b0;
    a0 = a1; b0 = b1;
    if (s + 2 < KSTEPS - 1) {
      a1 = *(const float4*)&xr[(s + 2) * 32];
      b1 = *(const float4*)&xr[(s + 2) * 32 + 4];
    } else if (s + 2 == KSTEPS - 1) {
      if (g == 3) {
        float2 tt = *(const float2*)&xr[18 * 32];   // cols 600,601
        a1 = make_float4(tt.x, tt.y, 0.f, 0.f);
        b1 = make_float4(0.f, 0.f, 0.f, 0.f);
      } else {
        a1 = *(const float4*)&xr[18 * 32];
        b1 = *(const float4*)&xr[18 * 32 + 4];
      }
    }
    bf16x8 f0n, f1n;
    if (s + 1 < KSTEPS) {
      const size_t fb = ((size_t)((s + 1) * 2) * 64 + lane) * 8;
      f0n = *(const bf16x8*)&Bh[fb];
      f1n = *(const bf16x8*)&Bh[fb + 512];
    }
    bf16x8 ahi, alo;
    {
      float cv0[8] = {ca.x, ca.y, ca.z, ca.w, cb.x, cb.y, cb.z, cb.w};
      #pragma unroll
      for (int j = 0; j < 8; ++j) {
        unsigned ub = __float_as_uint(cv0[j]);
        unsigned short h = (unsigned short)(ub >> 16);
        float hv = __uint_as_float(ub & 0xffff0000u);
        float d = cv0[j] - hv;
        ahi[j] = (short)h;
        alo[j] = (short)(__float_as_uint(d) >> 16);
      }
    }
    acc0 = __builtin_amdgcn_mfma_f32_16x16x32_bf16(ahi, f0c, acc0, 0, 0, 0);
    acc1 = __builtin_amdgcn_mfma_f32_16x16x32_bf16(ahi, f1c, acc1, 0, 0, 0);
    acc0 = __builtin_amdgcn_mfma_f32_16x16x32_bf16(alo, f0c, acc0, 0, 0, 0);
    acc1 = __builtin_amdgcn_mfma_f32_16x16x32_bf16(alo, f1c, acc1, 0, 0, 0);
    if (s + 1 < KSTEPS) { f0c = f0n; f1c = f1n; }
  }
  const int c0 = lane & 15;
  const float cva = cvec[c0], cvb = cvec[16 + c0];
  #pragma unroll
  for (int j = 0; j < 4; ++j) {
    int rr = row0 + g * 4 + j;
    zb[(size_t)rr * DD + c0] = f2b(acc0[j] + cva);
    zb[(size_t)rr * DD + 16 + c0] = f2b(acc1[j] + cvb);
  }
}

// ---------------- K3 fused: gather(self+edges of zb) in 4-lane/node shape -> LDS -> MLP1 ; stats
__global__ __launch_bounds__(256) void k3_fused(
    const unsigned short* __restrict__ zb,
    const int* __restrict__ rsA, const int* __restrict__ reA,
    const int* __restrict__ srcidx,
    const float* __restrict__ w2, const float* __restrict__ b1, const float* __restrict__ b2,
    unsigned short* __restrict__ g1b, float* __restrict__ stats) {
  __shared__ float us[64][DD + 1];
  __shared__ float w2s[DD * DD];
  __shared__ float b1s[DD], b2s[DD];
  __shared__ float ps[4][2 * DD];
  const int tid = threadIdx.x;
  const int nl = tid >> 2, q = tid & 3;
  const int n = blockIdx.x * 64 + nl;
  const bool valid = n < NN;
  for (int i = tid; i < DD * DD; i += 256) w2s[i] = w2[i];
  if (tid < DD) b1s[tid] = b1[tid];
  else if (tid < 2 * DD) b2s[tid - DD] = b2[tid - DD];

  float a[8] = {};
  if (valid) {
    // self row
    uint4 v = *(const uint4*)&zb[(size_t)n * DD + q * 8];
    a[0] = blo(v.x); a[1] = bhi(v.x); a[2] = blo(v.y); a[3] = bhi(v.y);
    a[4] = blo(v.z); a[5] = bhi(v.z); a[6] = blo(v.w); a[7] = bhi(v.w);
    int beg = rsA[n], end = reA[n];
    int i = beg;
    for (; i + 4 <= end; i += 4) {
      int s0 = srcidx[i], s1 = srcidx[i + 1], s2 = srcidx[i + 2], s3 = srcidx[i + 3];
      uint4 v0 = *(const uint4*)&zb[(size_t)s0 * DD + q * 8];
      uint4 v1 = *(const uint4*)&zb[(size_t)s1 * DD + q * 8];
      uint4 v2 = *(const uint4*)&zb[(size_t)s2 * DD + q * 8];
      uint4 v3 = *(const uint4*)&zb[(size_t)s3 * DD + q * 8];
      a[0] += blo(v0.x) + blo(v1.x) + blo(v2.x) + blo(v3.x);
      a[1] += bhi(v0.x) + bhi(v1.x) + bhi(v2.x) + bhi(v3.x);
      a[2] += blo(v0.y) + blo(v1.y) + blo(v2.y) + blo(v3.y);
      a[3] += bhi(v0.y) + bhi(v1.y) + bhi(v2.y) + bhi(v3.y);
      a[4] += blo(v0.z) + blo(v1.z) + blo(v2.z) + blo(v3.z);
      a[5] += bhi(v0.z) + bhi(v1.z) + bhi(v2.z) + bhi(v3.z);
      a[6] += blo(v0.w) + blo(v1.w) + blo(v2.w) + blo(v3.w);
      a[7] += bhi(v0.w) + bhi(v1.w) + bhi(v2.w) + bhi(v3.w);
    }
    for (; i < end; ++i) {
      uint4 v0 = *(const uint4*)&zb[(size_t)srcidx[i] * DD + q * 8];
      a[0] += blo(v0.x); a[1] += bhi(v0.x);
      a[2] += blo(v0.y); a[3] += bhi(v0.y);
      a[4] += blo(v0.z); a[5] += bhi(v0.z);
      a[6] += blo(v0.w); a[7] += bhi(v0.w);
    }
  }
  #pragma unroll
  for (int j = 0; j < 8; ++j) us[nl][q * 8 + j] = a[j];
  __syncthreads();
  // MLP1: t = relu(u + b1); g = t @ w2 + b2   (4 lanes/node, 8 cols each)
  float g[8];
  #pragma unroll
  for (int j = 0; j < 8; ++j) g[j] = b2s[q * 8 + j];
  #pragma unroll
  for (int k = 0; k < DD; ++k) {
    float tv = fmaxf(us[nl][k] + b1s[k], 0.f);
    #pragma unroll
    for (int j = 0; j < 8; ++j) g[j] = fmaf(tv, w2s[k * DD + q * 8 + j], g[j]);
  }
  // stats: per-channel sum/sumsq over this wave's 16 nodes (xor over nl bits)
  int wave = tid >> 6;
  float sv[8], sq[8];
  #pragma unroll
  for (int j = 0; j < 8; ++j) { sv[j] = valid ? g[j] : 0.f; sq[j] = sv[j] * sv[j]; }
  #pragma unroll
  for (int j = 0; j < 8; ++j) {
    #pragma unroll
    for (int off = 4; off < 64; off <<= 1) { sv[j] += __shfl_xor(sv[j], off); sq[j] += __shfl_xor(sq[j], off); }
  }
  if ((tid & 63) < 4) {
    #pragma unroll
    for (int j = 0; j < 8; ++j) { ps[wave][q * 8 + j] = sv[j]; ps[wave][DD + q * 8 + j] = sq[j]; }
  }
  __syncthreads();
  if (tid < 2 * DD)
    atomAdd(&stats[tid], ps[0][tid] + ps[1][tid] + ps[2][tid] + ps[3][tid]);
  if (valid) {
    unsigned u0 = ((unsigned)f2b(g[1]) << 16) | f2b(g[0]);
    unsigned u1 = ((unsigned)f2b(g[3]) << 16) | f2b(g[2]);
    unsigned u2 = ((unsigned)f2b(g[5]) << 16) | f2b(g[4]);
    unsigned u3 = ((unsigned)f2b(g[7]) << 16) | f2b(g[6]);
    *(uint4*)&g1b[(size_t)n * DD + q * 8] = make_uint4(u0, u1, u2, u3);
  }
}

// ---------------- K3b: BN1 params as (rs, sh): bn(y) = y*rs + sh
__global__ void k3b_bn(const float* __restrict__ stats, const float* __restrict__ gamma,
                       const float* __restrict__ beta, float* __restrict__ bnp) {
  int t = threadIdx.x;
  if (t < DD) {
    float mu = stats[t] * (1.f / NN);
    float var = stats[DD + t] * (1.f / NN) - mu * mu;
    float rsv = rsqrtf(var + BN_EPS) * gamma[t];
    bnp[t] = rsv;
    bnp[DD + t] = beta[t] - mu * rsv;
  }
}

// ---------------- K6 fused: gather raw g1b -> BN-affine (deg+1 fold) -> 2-layer MLP ; stats2
__global__ __launch_bounds__(256) void k6_fused(
    const unsigned short* __restrict__ g1b,
    const int* __restrict__ rsA, const int* __restrict__ reA,
    const int* __restrict__ srcidx, const float* __restrict__ bnp,
    const float* __restrict__ w1, const float* __restrict__ b1,
    const float* __restrict__ w2, const float* __restrict__ b2,
    float* __restrict__ g2, float* __restrict__ stats) {
  __shared__ float us[64][DD + 1];
  __shared__ float ts[64][DD + 1];
  __shared__ float w1s[DD * DD];
  __shared__ float w2s[DD * DD];
  __shared__ float bns[2 * DD];
  __shared__ float b1s[DD], b2s[DD];
  __shared__ float ps[4][2 * DD];
  const int tid = threadIdx.x;
  const int nl = tid >> 2, q = tid & 3;
  const int n = blockIdx.x * 64 + nl;
  const bool valid = n < NN;
  for (int i = tid; i < DD * DD; i += 256) { w1s[i] = w1[i]; w2s[i] = w2[i]; }
  if (tid < 2 * DD) bns[tid] = bnp[tid];
  if (tid < DD) b1s[tid] = b1[tid];
  else if (tid < 2 * DD) b2s[tid - DD] = b2[tid - DD];

  float a[8] = {};
  float degp1 = 1.f;
  if (valid) {
    uint4 v = *(const uint4*)&g1b[(size_t)n * DD + q * 8];
    a[0] = blo(v.x); a[1] = bhi(v.x); a[2] = blo(v.y); a[3] = bhi(v.y);
    a[4] = blo(v.z); a[5] = bhi(v.z); a[6] = blo(v.w); a[7] = bhi(v.w);
    int beg = rsA[n], end = reA[n];
    degp1 = (float)(end - beg + 1);
    int i = beg;
    for (; i + 4 <= end; i += 4) {
      int s0 = srcidx[i], s1 = srcidx[i + 1], s2 = srcidx[i + 2], s3 = srcidx[i + 3];
      uint4 v0 = *(const uint4*)&g1b[(size_t)s0 * DD + q * 8];
      uint4 v1 = *(const uint4*)&g1b[(size_t)s1 * DD + q * 8];
      uint4 v2 = *(const uint4*)&g1b[(size_t)s2 * DD + q * 8];
      uint4 v3 = *(const uint4*)&g1b[(size_t)s3 * DD + q * 8];
      a[0] += blo(v0.x) + blo(v1.x) + blo(v2.x) + blo(v3.x);
      a[1] += bhi(v0.x) + bhi(v1.x) + bhi(v2.x) + bhi(v3.x);
      a[2] += blo(v0.y) + blo(v1.y) + blo(v2.y) + blo(v3.y);
      a[3] += bhi(v0.y) + bhi(v1.y) + bhi(v2.y) + bhi(v3.y);
      a[4] += blo(v0.z) + blo(v1.z) + blo(v2.z) + blo(v3.z);
      a[5] += bhi(v0.z) + bhi(v1.z) + bhi(v2.z) + bhi(v3.z);
      a[6] += blo(v0.w) + blo(v1.w) + blo(v2.w) + blo(v3.w);
      a[7] += bhi(v0.w) + bhi(v1.w) + bhi(v2.w) + bhi(v3.w);
    }
    for (; i < end; ++i) {
      uint4 v0 = *(const uint4*)&g1b[(size_t)srcidx[i] * DD + q * 8];
      a[0] += blo(v0.x); a[1] += bhi(v0.x);
      a[2] += blo(v0.y); a[3] += bhi(v0.y);
      a[4] += blo(v0.z); a[5] += bhi(v0.z);
      a[6] += blo(v0.w); a[7] += bhi(v0.w);
    }
  }
  #pragma unroll
  for (int j = 0; j < 8; ++j) us[nl][q * 8 + j] = a[j];
  __syncthreads();
  // layer 1: u[k] = us*rs + degp1*sh ; t1 = relu(u @ w1 + b1)
  float t1[8];
  #pragma unroll
  for (int j = 0; j < 8; ++j) t1[j] = b1s[q * 8 + j];
  #pragma unroll
  for (int k = 0; k < DD; ++k) {
    float uv = fmaf(us[nl][k], bns[k], degp1 * bns[DD + k]);
    #pragma unroll
    for (int j = 0; j < 8; ++j) t1[j] = fmaf(uv, w1s[k * DD + q * 8 + j], t1[j]);
  }
  #pragma unroll
  for (int j = 0; j < 8; ++j) ts[nl][q * 8 + j] = fmaxf(t1[j], 0.f);
  __syncthreads();
  // layer 2: g = t1 @ w2 + b2
  float g[8];
  #pragma unroll
  for (int j = 0; j < 8; ++j) g[j] = b2s[q * 8 + j];
  #pragma unroll
  for (int k = 0; k < DD; ++k) {
    float tv = ts[nl][k];
    #pragma unroll
    for (int j = 0; j < 8; ++j) g[j] = fmaf(tv, w2s[k * DD + q * 8 + j], g[j]);
  }
  // stats2
  int wave = tid >> 6;
  float sv[8], sq[8];
  #pragma unroll
  for (int j = 0; j < 8; ++j) { sv[j] = valid ? g[j] : 0.f; sq[j] = sv[j] * sv[j]; }
  #pragma unroll
  for (int j = 0; j < 8; ++j) {
    #pragma unroll
    for (int off = 4; off < 64; off <<= 1) { sv[j] += __shfl_xor(sv[j], off); sq[j] += __shfl_xor(sq[j], off); }
  }
  if ((tid & 63) < 4) {
    #pragma unroll
    for (int j = 0; j < 8; ++j) { ps[wave][q * 8 + j] = sv[j]; ps[wave][DD + q * 8 + j] = sq[j]; }
  }
  __syncthreads();
  if (tid < 2 * DD)
    atomAdd(&stats[tid], ps[0][tid] + ps[1][tid] + ps[2][tid] + ps[3][tid]);
  if (valid) {
    float* gp = &g2[(size_t)n * DD + q * 8];
    *(float4*)&gp[0] = make_float4(g[0], g[1], g[2], g[3]);
    *(float4*)&gp[4] = make_float4(g[4], g[5], g[6], g[7]);
  }
}

// ---------------- K7: out = relu(bn2(g2)@fc1+b)@fc2+b
__global__ __launch_bounds__(256) void k7_head(
    const float* __restrict__ g2, const float* __restrict__ stats2,
    const float* __restrict__ bn2_g, const float* __restrict__ bn2_b,
    const float* __restrict__ fc1_w, const float* __restrict__ fc1_b,
    const float* __restrict__ fc2_w, const float* __restrict__ fc2_b,
    float* __restrict__ out) {
  __shared__ float buf[256 * 42];
  __shared__ float fc1s[DD * DD];
  __shared__ float fc2s[DD * CC];
  __shared__ float mu2[DD], rsg2[DD], bet2[DD];
  const int tid = threadIdx.x;
  const int n0 = blockIdx.x * 256;
  if (tid < DD) {
    float mu = stats2[tid] * (1.f / NN);
    float var = stats2[DD + tid] * (1.f / NN) - mu * mu;
    mu2[tid] = mu;
    rsg2[tid] = rsqrtf(var + BN_EPS) * bn2_g[tid];
    bet2[tid] = bn2_b[tid];
  }
  for (int i = tid; i < DD * DD; i += 256) fc1s[i] = fc1_w[i];
  for (int i = tid; i < DD * CC; i += 256) fc2s[i] = fc2_w[i];
  __syncthreads();
  #pragma unroll
  for (int i = 0; i < 32; ++i) {
    int l = tid + i * 256;
    int r = l >> 5, c = l & 31;
    float v = 0.f;
    if (n0 + r < NN) v = (g2[(size_t)(n0 + r) * DD + c] - mu2[c]) * rsg2[c] + bet2[c];
    buf[r * 33 + c] = v;
  }
  __syncthreads();
  float t[DD];
  #pragma unroll
  for (int j = 0; j < DD; ++j) t[j] = fc1_b[j];
  #pragma unroll
  for (int k = 0; k < DD; ++k) {
    float uv = buf[tid * 33 + k];
    #pragma unroll
    for (int j = 0; j < DD; ++j) t[j] = fmaf(uv, fc1s[k * DD + j], t[j]);
  }
  #pragma unroll
  for (int j = 0; j < DD; ++j) t[j] = fmaxf(t[j], 0.f);
  float o[CC];
  #pragma unroll
  for (int j = 0; j < CC; ++j) o[j] = fc2_b[j];
  #pragma unroll
  for (int k = 0; k < DD; ++k) {
    float tv = t[k];
    #pragma unroll
    for (int j = 0; j < CC; ++j) o[j] = fmaf(tv, fc2s[k * CC + j], o[j]);
  }
  __syncthreads();
  #pragma unroll
  for (int j = 0; j < CC; ++j) buf[tid * 42 + j] = o[j];
  __syncthreads();
  for (int i = 0; i < CC; ++i) {
    int l = tid + i * 256;
    int r = l / CC, c = l % CC;
    if (n0 + r < NN) out[(size_t)(n0 + r) * CC + c] = buf[r * 42 + c];
  }
}

extern "C" void kernel_launch(void* const* d_in, const int* in_sizes, int n_in,
                              void* d_out, int out_size, void* d_ws, size_t ws_size,
                              hipStream_t stream) {
  const float* x      = (const float*)d_in[0];
  const int*   ei     = (const int*)d_in[1];
  const float* lin1_w = (const float*)d_in[2];
  const float* lin1_b = (const float*)d_in[3];
  const float* nn1_w1 = (const float*)d_in[4];
  const float* nn1_b1 = (const float*)d_in[5];
  const float* nn1_w2 = (const float*)d_in[6];
  const float* nn1_b2 = (const float*)d_in[7];
  const float* bn1_g  = (const float*)d_in[8];
  const float* bn1_b  = (const float*)d_in[9];
  const float* nn2_w1 = (const float*)d_in[10];
  const float* nn2_b1 = (const float*)d_in[11];
  const float* nn2_w2 = (const float*)d_in[12];
  const float* nn2_b2 = (const float*)d_in[13];
  const float* bn2_g  = (const float*)d_in[14];
  const float* bn2_b  = (const float*)d_in[15];
  const float* fc1_w  = (const float*)d_in[16];
  const float* fc1_b  = (const float*)d_in[17];
  const float* fc2_w  = (const float*)d_in[18];
  const float* fc2_b  = (const float*)d_in[19];
  float* out = (float*)d_out;

  float* ws = (float*)d_ws;
  size_t nd = (size_t)NN * DD;
  float* A      = ws;            // g2 (f32)
  float* B      = ws + nd;       // g1b lives here (agg eliminated)
  float* cvec   = ws + 2 * nd;
  float* stats1 = cvec + 32;
  float* bnp1   = stats1 + 64;
  float* stats2 = bnp1 + 96;
  unsigned short* Bh = (unsigned short*)(stats2 + 64);      // 19456 shorts (38 KB)
  int*   rsA      = (int*)(Bh + KSTEPS * 2 * 64 * 8);       // NN
  int*   reA      = rsA + NN;                               // NN
  int*   srcidx   = reA + NN;                               // NB*BST
  int*   tsrc     = srcidx + (size_t)NB * BST;              // NB*BST ints; dead after kb_fine
  unsigned char* tdst = (unsigned char*)(tsrc + (size_t)NB * BST);  // NB*BST bytes
  int*   bcursor  = (int*)(tdst + (size_t)NB * BST);        // NB
  unsigned short* zb  = (unsigned short*)tsrc;              // aliases dead tsrc (7.2MB >= 6.4MB)
  unsigned short* g1b = (unsigned short*)B;                 // separate from zb (cross-block reads)

  // single-pass bucketed CSR build
  hipMemsetAsync(bcursor, 0, NB * sizeof(int), stream);
  kb_scatter<<<SCB, 256, 0, stream>>>(ei, bcursor, tsrc, tdst);
  kb_fine<<<NB, 256, 0, stream>>>(bcursor, tsrc, tdst, rsA, reA, srcidx);

  k0_prep<<<(KSTEPS * 32 * 32 + 255) / 256, 256, 0, stream>>>(
      lin1_w, lin1_b, nn1_w1, Bh, cvec, stats1, stats2);
  k1_mfma<<<(NN / 16 + 3) / 4, 256, 0, stream>>>(x, Bh, cvec, zb);
  k3_fused<<<(NN + 63) / 64, 256, 0, stream>>>(zb, rsA, reA, srcidx,
                                               nn1_w2, nn1_b1, nn1_b2, g1b, stats1);
  k3b_bn<<<1, 64, 0, stream>>>(stats1, bn1_g, bn1_b, bnp1);
  k6_fused<<<(NN + 63) / 64, 256, 0, stream>>>(g1b, rsA, reA, srcidx, bnp1,
                                               nn2_w1, nn2_b1, nn2_w2, nn2_b2, A, stats2);
  k7_head<<<(NN + 255) / 256, 256, 0, stream>>>(A, stats2, bn2_g, bn2_b, fc1_w, fc1_b, fc2_w, fc2_b, out);
}

// Round 14
// 269.031 us; speedup vs baseline: 1.0574x; 1.0574x over previous
//
#include <hip/hip_runtime.h>
#include <cstdint>

#define NN 100000
#define NE 1600000
#define FI 602
#define DD 32
#define CC 41
#define BN_EPS 1e-5f
#define KSTEPS 19                 // 19*32 = 608 >= 602 (k-padded with zeros)

// single-pass bucketed CSR build
#define NPB 256                   // nodes per bucket (dst >> 8)
#define NB 391                    // ceil(NN/NPB)
#define BST 4608                  // fixed bucket stride (mean 4096, sigma 64 -> 8-sigma margin)
#define EPT 13                    // edges per thread in scatter
#define SCB 481                   // ceil(NE / (256*EPT))

typedef __attribute__((ext_vector_type(8))) short bf16x8;
typedef __attribute__((ext_vector_type(4))) float f32x4;

__device__ __forceinline__ void atomAdd(float* p, float v) {
#ifdef __HIP_PLATFORM_AMD__
  unsafeAtomicAdd(p, v);
#else
  atomicAdd(p, v);
#endif
}

// round-to-nearest-even f32 -> bf16 bits
__device__ __forceinline__ unsigned short f2b(float f) {
  unsigned u = __float_as_uint(f);
  unsigned r = (u + 0x7fffu + ((u >> 16) & 1u)) >> 16;
  return (unsigned short)r;
}
__device__ __forceinline__ float blo(unsigned u) { return __uint_as_float(u << 16); }
__device__ __forceinline__ float bhi(unsigned u) { return __uint_as_float(u & 0xffff0000u); }

// ---------------- K0: M = lin1_w @ nn1_w1 as MFMA B-fragments (single RNE bf16) ; cvec ; zero stats
__global__ __launch_bounds__(256) void k0_prep(
    const float* __restrict__ lin1_w, const float* __restrict__ lin1_b,
    const float* __restrict__ nn1_w1,
    unsigned short* __restrict__ Bh,
    float* __restrict__ cvec,
    float* __restrict__ stats1, float* __restrict__ stats2) {
  int o = blockIdx.x * 256 + threadIdx.x;   // over 608*32
  if (o < KSTEPS * 32 * 32) {
    int k = o >> 5, j = o & 31;
    float s = 0.f;
    if (k < FI) {
      #pragma unroll 4
      for (int c = 0; c < 2 * DD; ++c) s = fmaf(lin1_w[k * (2 * DD) + c], nn1_w1[c * DD + j], s);
    }
    int st = k >> 5, kk = k & 31, g = kk >> 3, jj = kk & 7;
    int h = j >> 4, lane = g * 16 + (j & 15);
    int idx = ((st * 2 + h) * 64 + lane) * 8 + jj;
    Bh[idx] = f2b(s);
  }
  if (blockIdx.x == 0) {
    int t = threadIdx.x;
    if (t < DD) {
      float s = 0.f;
      for (int c = 0; c < 2 * DD; ++c) s = fmaf(lin1_b[c], nn1_w1[c * DD + t], s);
      cvec[t] = s;
    }
    if (t >= 128 && t < 192) stats1[t - 128] = 0.f;
    if (t >= 192) stats2[t - 192] = 0.f;
  }
}

// ---------------- single-pass scatter into fixed-stride buckets ----------------
__global__ __launch_bounds__(256) void kb_scatter(const int* __restrict__ ei,
                                                  int* __restrict__ bcursor,
                                                  int* __restrict__ tsrc,
                                                  unsigned char* __restrict__ tdst) {
  __shared__ int cnt[NB];
  __shared__ int wbase[NB];
  const int t = threadIdx.x;
  for (int i = t; i < NB; i += 256) cnt[i] = 0;
  __syncthreads();
  const int base = blockIdx.x * (256 * EPT);
  int s[EPT], d[EPT];
  #pragma unroll
  for (int i = 0; i < EPT; ++i) {
    int e = base + i * 256 + t;
    if (e < NE) {
      s[i] = ei[e];
      d[i] = ei[NE + e];
      atomicAdd(&cnt[d[i] >> 8], 1);
    } else {
      s[i] = -1; d[i] = -1;
    }
  }
  __syncthreads();
  for (int i = t; i < NB; i += 256) wbase[i] = atomicAdd(&bcursor[i], cnt[i]);
  __syncthreads();
  #pragma unroll
  for (int i = 0; i < EPT; ++i) {
    if (d[i] >= 0) {
      int bk = d[i] >> 8;
      int p = atomicAdd(&wbase[bk], 1);
      int gp = bk * BST + p;
      tsrc[gp] = s[i];
      tdst[gp] = (unsigned char)(d[i] & (NPB - 1));
    }
  }
}

// ---------------- per-bucket fine sort: rs/re + compact srcidx (bucket-strided CSR)
__global__ __launch_bounds__(256) void kb_fine(const int* __restrict__ bcursor,
                                               const int* __restrict__ tsrc,
                                               const unsigned char* __restrict__ tdst,
                                               int* __restrict__ rs, int* __restrict__ re,
                                               int* __restrict__ srcidx) {
  __shared__ int deg[NPB];
  __shared__ int cur[NPB];
  __shared__ int woff[4];
  const int b = blockIdx.x, t = threadIdx.x;
  const int beg = b * BST;
  const int end = beg + bcursor[b];
  deg[t] = 0;
  __syncthreads();
  for (int i = beg + t; i < end; i += 256) atomicAdd(&deg[tdst[i]], 1);
  __syncthreads();
  int v = deg[t];
  int lane = t & 63, wave = t >> 6;
  int inc = v;
  #pragma unroll
  for (int off = 1; off < 64; off <<= 1) {
    int u = __shfl_up(inc, off);
    if (lane >= off) inc += u;
  }
  if (lane == 63) woff[wave] = inc;
  __syncthreads();
  int wadd = 0;
  for (int w = 0; w < wave; ++w) wadd += woff[w];
  int excl = wadd + inc - v;
  int gnode = b * NPB + t;
  if (gnode < NN) {
    rs[gnode] = beg + excl;
    re[gnode] = beg + excl + v;
  }
  cur[t] = beg + excl;
  __syncthreads();
  for (int i = beg + t; i < end; i += 256) {
    int p = atomicAdd(&cur[tdst[i]], 1);
    srcidx[p] = tsrc[i];
  }
}

// ---------------- K1 v8 (MFMA, k-split): zb = bf16(x @ M + cvec)
// Block = 256 thr = 4 waves: wave w -> (rowgroup rg=w&1, khalf kh=w>>1).
// 3125 blocks x 32 rows = 100000 exactly (no row guards). kh0: steps 0..9,
// kh1: steps 10..18 (+tail guard). Partial accs combined through padded LDS.
// 12500 waves -> 8 waves/SIMD; depth-2 x prefetch -> 16 loads in flight/SIMD.
__global__ __launch_bounds__(256) void k1_mfma(
    const float* __restrict__ x,
    const unsigned short* __restrict__ Bh,
    const float* __restrict__ cvec, unsigned short* __restrict__ zb) {
  __shared__ float part[2][64][9];
  const int tid = threadIdx.x;
  const int lane = tid & 63;
  const int w = tid >> 6;
  const int rg = w & 1;
  const int kh = w >> 1;
  const int row0 = blockIdx.x * 32 + rg * 16;
  const int g = lane >> 4;
  const int r = row0 + (lane & 15);
  const float* __restrict__ xr = x + (size_t)r * FI + g * 8;
  f32x4 acc0 = {0.f, 0.f, 0.f, 0.f};
  f32x4 acc1 = {0.f, 0.f, 0.f, 0.f};

  if (kh == 0) {
    // steps 0..9, all unguarded (max k = 288+31 = 319 < 602)
    float4 a0 = *(const float4*)&xr[0];
    float4 b0 = *(const float4*)&xr[4];
    float4 a1 = *(const float4*)&xr[32];
    float4 b1 = *(const float4*)&xr[36];
    bf16x8 f0c = *(const bf16x8*)&Bh[(size_t)lane * 8];
    bf16x8 f1c = *(const bf16x8*)&Bh[(size_t)lane * 8 + 512];
    #pragma unroll
    for (int s = 0; s < 10; ++s) {
      float4 ca = a0, cb = b0;
      a0 = a1; b0 = b1;
      if (s + 2 < 10) {
        a1 = *(const float4*)&xr[(s + 2) * 32];
        b1 = *(const float4*)&xr[(s + 2) * 32 + 4];
      }
      bf16x8 f0n, f1n;
      if (s + 1 < 10) {
        const size_t fb = ((size_t)((s + 1) * 2) * 64 + lane) * 8;
        f0n = *(const bf16x8*)&Bh[fb];
        f1n = *(const bf16x8*)&Bh[fb + 512];
      }
      bf16x8 ahi, alo;
      float cv0[8] = {ca.x, ca.y, ca.z, ca.w, cb.x, cb.y, cb.z, cb.w};
      #pragma unroll
      for (int j = 0; j < 8; ++j) {
        unsigned ub = __float_as_uint(cv0[j]);
        unsigned short h = (unsigned short)(ub >> 16);
        float hv = __uint_as_float(ub & 0xffff0000u);
        float d = cv0[j] - hv;
        ahi[j] = (short)h;
        alo[j] = (short)(__float_as_uint(d) >> 16);
      }
      acc0 = __builtin_amdgcn_mfma_f32_16x16x32_bf16(ahi, f0c, acc0, 0, 0, 0);
      acc1 = __builtin_amdgcn_mfma_f32_16x16x32_bf16(ahi, f1c, acc1, 0, 0, 0);
      acc0 = __builtin_amdgcn_mfma_f32_16x16x32_bf16(alo, f0c, acc0, 0, 0, 0);
      acc1 = __builtin_amdgcn_mfma_f32_16x16x32_bf16(alo, f1c, acc1, 0, 0, 0);
      if (s + 1 < 10) { f0c = f0n; f1c = f1n; }
    }
  } else {
    // steps 10..18; steps 10..17 unguarded (max k = 544+31 = 575 < 602);
    // step 18: k = 576+g*8, g==3 -> only cols 600,601 valid.
    float4 a0 = *(const float4*)&xr[10 * 32];
    float4 b0 = *(const float4*)&xr[10 * 32 + 4];
    float4 a1 = *(const float4*)&xr[11 * 32];
    float4 b1 = *(const float4*)&xr[11 * 32 + 4];
    bf16x8 f0c = *(const bf16x8*)&Bh[((size_t)(10 * 2) * 64 + lane) * 8];
    bf16x8 f1c = *(const bf16x8*)&Bh[((size_t)(10 * 2) * 64 + lane) * 8 + 512];
    #pragma unroll
    for (int s = 10; s < KSTEPS; ++s) {
      float4 ca = a0, cb = b0;
      a0 = a1; b0 = b1;
      if (s + 2 < KSTEPS - 1) {
        a1 = *(const float4*)&xr[(s + 2) * 32];
        b1 = *(const float4*)&xr[(s + 2) * 32 + 4];
      } else if (s + 2 == KSTEPS - 1) {
        if (g == 3) {
          float2 tt = *(const float2*)&xr[18 * 32];   // cols 600,601
          a1 = make_float4(tt.x, tt.y, 0.f, 0.f);
          b1 = make_float4(0.f, 0.f, 0.f, 0.f);
        } else {
          a1 = *(const float4*)&xr[18 * 32];
          b1 = *(const float4*)&xr[18 * 32 + 4];
        }
      }
      bf16x8 f0n, f1n;
      if (s + 1 < KSTEPS) {
        const size_t fb = ((size_t)((s + 1) * 2) * 64 + lane) * 8;
        f0n = *(const bf16x8*)&Bh[fb];
        f1n = *(const bf16x8*)&Bh[fb + 512];
      }
      bf16x8 ahi, alo;
      float cv0[8] = {ca.x, ca.y, ca.z, ca.w, cb.x, cb.y, cb.z, cb.w};
      #pragma unroll
      for (int j = 0; j < 8; ++j) {
        unsigned ub = __float_as_uint(cv0[j]);
        unsigned short h = (unsigned short)(ub >> 16);
        float hv = __uint_as_float(ub & 0xffff0000u);
        float d = cv0[j] - hv;
        ahi[j] = (short)h;
        alo[j] = (short)(__float_as_uint(d) >> 16);
      }
      acc0 = __builtin_amdgcn_mfma_f32_16x16x32_bf16(ahi, f0c, acc0, 0, 0, 0);
      acc1 = __builtin_amdgcn_mfma_f32_16x16x32_bf16(ahi, f1c, acc1, 0, 0, 0);
      acc0 = __builtin_amdgcn_mfma_f32_16x16x32_bf16(alo, f0c, acc0, 0, 0, 0);
      acc1 = __builtin_amdgcn_mfma_f32_16x16x32_bf16(alo, f1c, acc1, 0, 0, 0);
      if (s + 1 < KSTEPS) { f0c = f0n; f1c = f1n; }
    }
    #pragma unroll
    for (int j = 0; j < 4; ++j) {
      part[rg][lane][j] = acc0[j];
      part[rg][lane][4 + j] = acc1[j];
    }
  }
  __syncthreads();
  if (kh == 0) {
    const int c0 = lane & 15;
    const float cva = cvec[c0], cvb = cvec[16 + c0];
    #pragma unroll
    for (int j = 0; j < 4; ++j) {
      float v0 = acc0[j] + part[rg][lane][j] + cva;
      float v1 = acc1[j] + part[rg][lane][4 + j] + cvb;
      int rr = row0 + g * 4 + j;
      zb[(size_t)rr * DD + c0] = f2b(v0);
      zb[(size_t)rr * DD + 16 + c0] = f2b(v1);
    }
  }
}

// ---------------- gather (bf16 operand, depth-8): agg[n] = sum of src rows
__global__ __launch_bounds__(256) void k_gather_b(const int* __restrict__ rs,
                                                  const int* __restrict__ re,
                                                  const int* __restrict__ srcidx,
                                                  const unsigned short* __restrict__ srcb,
                                                  float* __restrict__ agg) {
  int gid = blockIdx.x * 256 + threadIdx.x;
  int n = gid >> 2, q = gid & 3;
  if (n >= NN) return;
  int beg = rs[n], end = re[n];
  float a[8] = {};
  int i = beg;
  for (; i + 8 <= end; i += 8) {
    uint4 v[8];
    #pragma unroll
    for (int j = 0; j < 8; ++j) v[j] = *(const uint4*)&srcb[(size_t)srcidx[i + j] * DD + q * 8];
    #pragma unroll
    for (int j = 0; j < 8; ++j) {
      a[0] += blo(v[j].x); a[1] += bhi(v[j].x);
      a[2] += blo(v[j].y); a[3] += bhi(v[j].y);
      a[4] += blo(v[j].z); a[5] += bhi(v[j].z);
      a[6] += blo(v[j].w); a[7] += bhi(v[j].w);
    }
  }
  for (; i + 4 <= end; i += 4) {
    uint4 v[4];
    #pragma unroll
    for (int j = 0; j < 4; ++j) v[j] = *(const uint4*)&srcb[(size_t)srcidx[i + j] * DD + q * 8];
    #pragma unroll
    for (int j = 0; j < 4; ++j) {
      a[0] += blo(v[j].x); a[1] += bhi(v[j].x);
      a[2] += blo(v[j].y); a[3] += bhi(v[j].y);
      a[4] += blo(v[j].z); a[5] += bhi(v[j].z);
      a[6] += blo(v[j].w); a[7] += bhi(v[j].w);
    }
  }
  for (; i < end; ++i) {
    uint4 v0 = *(const uint4*)&srcb[(size_t)srcidx[i] * DD + q * 8];
    a[0] += blo(v0.x); a[1] += bhi(v0.x);
    a[2] += blo(v0.y); a[3] += bhi(v0.y);
    a[4] += blo(v0.z); a[5] += bhi(v0.z);
    a[6] += blo(v0.w); a[7] += bhi(v0.w);
  }
  float* ap = &agg[(size_t)n * DD + q * 8];
  *(float4*)&ap[0] = make_float4(a[0], a[1], a[2], a[3]);
  *(float4*)&ap[4] = make_float4(a[4], a[5], a[6], a[7]);
}

// ---------------- K3: g1b = bf16(relu(zb+agg+b1) @ w2 + b2) ; stats (in-place zb->g1b)
__global__ __launch_bounds__(256) void k3_mlp1(
    const unsigned short* __restrict__ zb, const float* __restrict__ agg,
    const float* __restrict__ w2, const float* __restrict__ b1, const float* __restrict__ b2,
    unsigned short* __restrict__ g1b, float* __restrict__ stats) {
  __shared__ float us[256][DD + 1];
  __shared__ float w2s[DD][DD];
  __shared__ float ps[4][2 * DD];
  const int tid = threadIdx.x;
  const int n0 = blockIdx.x * 256;
  for (int i = tid; i < DD * DD; i += 256) w2s[i >> 5][i & 31] = w2[i];
  #pragma unroll
  for (int i = 0; i < 16; ++i) {
    int l = tid + i * 256;
    int r = l >> 4, c2 = l & 15;
    float lo = 0.f, hi = 0.f;
    if (n0 + r < NN) {
      size_t gi = (size_t)(n0 + r) * DD + c2 * 2;
      unsigned u = *(const unsigned*)&zb[gi];
      float2 ag = *(const float2*)&agg[gi];
      lo = blo(u) + ag.x;
      hi = bhi(u) + ag.y;
    }
    us[r][c2 * 2] = lo;
    us[r][c2 * 2 + 1] = hi;
  }
  __syncthreads();
  float t[DD];
  #pragma unroll
  for (int k = 0; k < DD; ++k) t[k] = fmaxf(us[tid][k] + b1[k], 0.f);
  float g[DD];
  #pragma unroll
  for (int j = 0; j < DD; ++j) g[j] = b2[j];
  #pragma unroll
  for (int k = 0; k < DD; ++k) {
    float tv = t[k];
    #pragma unroll
    for (int j = 0; j < DD; ++j) g[j] = fmaf(tv, w2s[k][j], g[j]);
  }
  bool valid = (n0 + tid) < NN;
  #pragma unroll
  for (int j = 0; j < DD; ++j) us[tid][j] = g[j];
  int wave = tid >> 6, lane = tid & 63;
  #pragma unroll
  for (int j = 0; j < DD; ++j) {
    float v = valid ? g[j] : 0.f;
    float qq = v * v;
    #pragma unroll
    for (int off = 1; off < 64; off <<= 1) { v += __shfl_xor(v, off); qq += __shfl_xor(qq, off); }
    if (lane == 0) { ps[wave][j] = v; ps[wave][DD + j] = qq; }
  }
  __syncthreads();
  if (tid < 2 * DD)
    atomAdd(&stats[tid], ps[0][tid] + ps[1][tid] + ps[2][tid] + ps[3][tid]);
  #pragma unroll
  for (int i = 0; i < 16; ++i) {
    int l = tid + i * 256;
    int r = l >> 4, c2 = l & 15;
    if (n0 + r < NN) {
      unsigned u = ((unsigned)f2b(us[r][c2 * 2 + 1]) << 16) | (unsigned)f2b(us[r][c2 * 2]);
      *(unsigned*)&g1b[(size_t)(n0 + r) * DD + c2 * 2] = u;
    }
  }
}

// ---------------- K6: BN1 params inline from stats1 ; u = (g1b+agg)*rs + (1+deg)*sh ;
// g2 = relu(u@w1+b1)@w2+b2 ; stats2
__global__ __launch_bounds__(256) void k6_mlp2(
    const unsigned short* __restrict__ g1b, const float* __restrict__ agg,
    const int* __restrict__ rsA, const int* __restrict__ reA,
    const float* __restrict__ stats1, const float* __restrict__ bn1_g, const float* __restrict__ bn1_b,
    const float* __restrict__ w1, const float* __restrict__ b1,
    const float* __restrict__ w2, const float* __restrict__ b2,
    float* __restrict__ g2, float* __restrict__ stats) {
  __shared__ float us[256][DD + 1];
  __shared__ float w1s[DD][DD];
  __shared__ float w2s[DD][DD];
  __shared__ float bns[2 * DD];
  __shared__ float ps[4][2 * DD];
  const int tid = threadIdx.x;
  const int n0 = blockIdx.x * 256;
  for (int i = tid; i < DD * DD; i += 256) { w1s[i >> 5][i & 31] = w1[i]; w2s[i >> 5][i & 31] = w2[i]; }
  if (tid < DD) {
    float mu = stats1[tid] * (1.f / NN);
    float var = stats1[DD + tid] * (1.f / NN) - mu * mu;
    float rsv = rsqrtf(var + BN_EPS) * bn1_g[tid];
    bns[tid] = rsv;
    bns[DD + tid] = bn1_b[tid] - mu * rsv;
  }
  const int n = n0 + tid;
  const bool valid = n < NN;
  float degp1 = 1.f;
  if (valid) degp1 = (float)(reA[n] - rsA[n] + 1);
  #pragma unroll
  for (int i = 0; i < 16; ++i) {
    int l = tid + i * 256;
    int r = l >> 4, c2 = l & 15;
    float lo = 0.f, hi = 0.f;
    if (n0 + r < NN) {
      size_t gi = (size_t)(n0 + r) * DD + c2 * 2;
      unsigned u = *(const unsigned*)&g1b[gi];
      float2 ag = *(const float2*)&agg[gi];
      lo = blo(u) + ag.x;
      hi = bhi(u) + ag.y;
    }
    us[r][c2 * 2] = lo;
    us[r][c2 * 2 + 1] = hi;
  }
  __syncthreads();
  float t1[DD];
  #pragma unroll
  for (int j = 0; j < DD; ++j) t1[j] = b1[j];
  #pragma unroll
  for (int k = 0; k < DD; ++k) {
    float uv = fmaf(us[tid][k], bns[k], degp1 * bns[DD + k]);
    #pragma unroll
    for (int j = 0; j < DD; ++j) t1[j] = fmaf(uv, w1s[k][j], t1[j]);
  }
  #pragma unroll
  for (int j = 0; j < DD; ++j) t1[j] = fmaxf(t1[j], 0.f);
  float g[DD];
  #pragma unroll
  for (int j = 0; j < DD; ++j) g[j] = b2[j];
  #pragma unroll
  for (int k = 0; k < DD; ++k) {
    float tv = t1[k];
    #pragma unroll
    for (int j = 0; j < DD; ++j) g[j] = fmaf(tv, w2s[k][j], g[j]);
  }
  #pragma unroll
  for (int j = 0; j < DD; ++j) us[tid][j] = g[j];
  int wave = tid >> 6, lane = tid & 63;
  #pragma unroll
  for (int j = 0; j < DD; ++j) {
    float v = valid ? g[j] : 0.f;
    float qq = v * v;
    #pragma unroll
    for (int off = 1; off < 64; off <<= 1) { v += __shfl_xor(v, off); qq += __shfl_xor(qq, off); }
    if (lane == 0) { ps[wave][j] = v; ps[wave][DD + j] = qq; }
  }
  __syncthreads();
  if (tid < 2 * DD)
    atomAdd(&stats[tid], ps[0][tid] + ps[1][tid] + ps[2][tid] + ps[3][tid]);
  #pragma unroll
  for (int i = 0; i < 32; ++i) {
    int l = tid + i * 256;
    int r = l >> 5, c = l & 31;
    if (n0 + r < NN) g2[(size_t)(n0 + r) * DD + c] = us[r][c];
  }
}

// ---------------- K7: out = relu(bn2(g2)@fc1+b)@fc2+b
__global__ __launch_bounds__(256) void k7_head(
    const float* __restrict__ g2, const float* __restrict__ stats2,
    const float* __restrict__ bn2_g, const float* __restrict__ bn2_b,
    const float* __restrict__ fc1_w, const float* __restrict__ fc1_b,
    const float* __restrict__ fc2_w, const float* __restrict__ fc2_b,
    float* __restrict__ out) {
  __shared__ float buf[256 * 42];
  __shared__ float fc1s[DD * DD];
  __shared__ float fc2s[DD * CC];
  __shared__ float mu2[DD], rsg2[DD], bet2[DD];
  const int tid = threadIdx.x;
  const int n0 = blockIdx.x * 256;
  if (tid < DD) {
    float mu = stats2[tid] * (1.f / NN);
    float var = stats2[DD + tid] * (1.f / NN) - mu * mu;
    mu2[tid] = mu;
    rsg2[tid] = rsqrtf(var + BN_EPS) * bn2_g[tid];
    bet2[tid] = bn2_b[tid];
  }
  for (int i = tid; i < DD * DD; i += 256) fc1s[i] = fc1_w[i];
  for (int i = tid; i < DD * CC; i += 256) fc2s[i] = fc2_w[i];
  __syncthreads();
  #pragma unroll
  for (int i = 0; i < 32; ++i) {
    int l = tid + i * 256;
    int r = l >> 5, c = l & 31;
    float v = 0.f;
    if (n0 + r < NN) v = (g2[(size_t)(n0 + r) * DD + c] - mu2[c]) * rsg2[c] + bet2[c];
    buf[r * 33 + c] = v;
  }
  __syncthreads();
  float t[DD];
  #pragma unroll
  for (int j = 0; j < DD; ++j) t[j] = fc1_b[j];
  #pragma unroll
  for (int k = 0; k < DD; ++k) {
    float uv = buf[tid * 33 + k];
    #pragma unroll
    for (int j = 0; j < DD; ++j) t[j] = fmaf(uv, fc1s[k * DD + j], t[j]);
  }
  #pragma unroll
  for (int j = 0; j < DD; ++j) t[j] = fmaxf(t[j], 0.f);
  float o[CC];
  #pragma unroll
  for (int j = 0; j < CC; ++j) o[j] = fc2_b[j];
  #pragma unroll
  for (int k = 0; k < DD; ++k) {
    float tv = t[k];
    #pragma unroll
    for (int j = 0; j < CC; ++j) o[j] = fmaf(tv, fc2s[k * CC + j], o[j]);
  }
  __syncthreads();
  #pragma unroll
  for (int j = 0; j < CC; ++j) buf[tid * 42 + j] = o[j];
  __syncthreads();
  for (int i = 0; i < CC; ++i) {
    int l = tid + i * 256;
    int r = l / CC, c = l % CC;
    if (n0 + r < NN) out[(size_t)(n0 + r) * CC + c] = buf[r * 42 + c];
  }
}

extern "C" void kernel_launch(void* const* d_in, const int* in_sizes, int n_in,
                              void* d_out, int out_size, void* d_ws, size_t ws_size,
                              hipStream_t stream) {
  const float* x      = (const float*)d_in[0];
  const int*   ei     = (const int*)d_in[1];
  const float* lin1_w = (const float*)d_in[2];
  const float* lin1_b = (const float*)d_in[3];
  const float* nn1_w1 = (const float*)d_in[4];
  const float* nn1_b1 = (const float*)d_in[5];
  const float* nn1_w2 = (const float*)d_in[6];
  const float* nn1_b2 = (const float*)d_in[7];
  const float* bn1_g  = (const float*)d_in[8];
  const float* bn1_b  = (const float*)d_in[9];
  const float* nn2_w1 = (const float*)d_in[10];
  const float* nn2_b1 = (const float*)d_in[11];
  const float* nn2_w2 = (const float*)d_in[12];
  const float* nn2_b2 = (const float*)d_in[13];
  const float* bn2_g  = (const float*)d_in[14];
  const float* bn2_b  = (const float*)d_in[15];
  const float* fc1_w  = (const float*)d_in[16];
  const float* fc1_b  = (const float*)d_in[17];
  const float* fc2_w  = (const float*)d_in[18];
  const float* fc2_b  = (const float*)d_in[19];
  float* out = (float*)d_out;

  float* ws = (float*)d_ws;
  size_t nd = (size_t)NN * DD;
  float* A      = ws;            // g2 (f32)
  float* B      = ws + nd;       // agg (raw f32)
  float* cvec   = ws + 2 * nd;
  float* stats1 = cvec + 32;
  float* stats2 = stats1 + 64;
  unsigned short* Bh = (unsigned short*)(stats2 + 64);      // 19456 shorts (38 KB)
  int*   rsA      = (int*)(Bh + KSTEPS * 2 * 64 * 8);       // NN
  int*   reA      = rsA + NN;                               // NN
  int*   srcidx   = reA + NN;                               // NB*BST
  int*   tsrc     = srcidx + (size_t)NB * BST;              // NB*BST ints; dead after kb_fine
  unsigned char* tdst = (unsigned char*)(tsrc + (size_t)NB * BST);  // NB*BST bytes
  int*   bcursor  = (int*)(tdst + (size_t)NB * BST);        // NB
  // bf16 feature buffer (zb, then g1b in place) aliases dead tsrc (7.2MB >= 6.4MB)
  unsigned short* fb16 = (unsigned short*)tsrc;

  // single-pass bucketed CSR build
  hipMemsetAsync(bcursor, 0, NB * sizeof(int), stream);
  kb_scatter<<<SCB, 256, 0, stream>>>(ei, bcursor, tsrc, tdst);
  kb_fine<<<NB, 256, 0, stream>>>(bcursor, tsrc, tdst, rsA, reA, srcidx);

  k0_prep<<<(KSTEPS * 32 * 32 + 255) / 256, 256, 0, stream>>>(
      lin1_w, lin1_b, nn1_w1, Bh, cvec, stats1, stats2);
  k1_mfma<<<NN / 32, 256, 0, stream>>>(x, Bh, cvec, fb16);
  k_gather_b<<<(NN * 4 + 255) / 256, 256, 0, stream>>>(rsA, reA, srcidx, fb16, B);
  k3_mlp1<<<(NN + 255) / 256, 256, 0, stream>>>(fb16, B, nn1_w2, nn1_b1, nn1_b2, fb16, stats1);
  k_gather_b<<<(NN * 4 + 255) / 256, 256, 0, stream>>>(rsA, reA, srcidx, fb16, B);
  k6_mlp2<<<(NN + 255) / 256, 256, 0, stream>>>(fb16, B, rsA, reA, stats1, bn1_g, bn1_b,
                                                nn2_w1, nn2_b1, nn2_w2, nn2_b2, A, stats2);
  k7_head<<<(NN + 255) / 256, 256, 0, stream>>>(A, stats2, bn2_g, bn2_b, fc1_w, fc1_b, fc2_w, fc2_b, out);
}

// Round 15
// 254.447 us; speedup vs baseline: 1.1180x; 1.0573x over previous
//
#include <hip/hip_runtime.h>
#include <cstdint>

#define NN 100000
#define NE 1600000
#define FI 602
#define DD 32
#define CC 41
#define BN_EPS 1e-5f
#define KSTEPS 19                 // 19*32 = 608 >= 602 (k-padded with zeros)

// single-pass bucketed CSR build
#define NPB 256                   // nodes per bucket (dst >> 8)
#define NB 391                    // ceil(NN/NPB)
#define BST 4608                  // fixed bucket stride (mean 4096, sigma 64 -> 8-sigma margin)
#define EPT 13                    // edges per thread in scatter
#define SCB 481                   // ceil(NE / (256*EPT))

typedef __attribute__((ext_vector_type(8))) short bf16x8;
typedef __attribute__((ext_vector_type(4))) float f32x4;

__device__ __forceinline__ void atomAdd(float* p, float v) {
#ifdef __HIP_PLATFORM_AMD__
  unsafeAtomicAdd(p, v);
#else
  atomicAdd(p, v);
#endif
}

// round-to-nearest-even f32 -> bf16 bits
__device__ __forceinline__ unsigned short f2b(float f) {
  unsigned u = __float_as_uint(f);
  unsigned r = (u + 0x7fffu + ((u >> 16) & 1u)) >> 16;
  return (unsigned short)r;
}
__device__ __forceinline__ float blo(unsigned u) { return __uint_as_float(u << 16); }
__device__ __forceinline__ float bhi(unsigned u) { return __uint_as_float(u & 0xffff0000u); }

// ---------------- K0: M = lin1_w @ nn1_w1 as MFMA B-fragments (single RNE bf16) ; cvec ; zero stats
__global__ __launch_bounds__(256) void k0_prep(
    const float* __restrict__ lin1_w, const float* __restrict__ lin1_b,
    const float* __restrict__ nn1_w1,
    unsigned short* __restrict__ Bh,
    float* __restrict__ cvec,
    float* __restrict__ stats1, float* __restrict__ stats2) {
  int o = blockIdx.x * 256 + threadIdx.x;   // over 608*32
  if (o < KSTEPS * 32 * 32) {
    int k = o >> 5, j = o & 31;
    float s = 0.f;
    if (k < FI) {
      #pragma unroll 4
      for (int c = 0; c < 2 * DD; ++c) s = fmaf(lin1_w[k * (2 * DD) + c], nn1_w1[c * DD + j], s);
    }
    int st = k >> 5, kk = k & 31, g = kk >> 3, jj = kk & 7;
    int h = j >> 4, lane = g * 16 + (j & 15);
    int idx = ((st * 2 + h) * 64 + lane) * 8 + jj;
    Bh[idx] = f2b(s);
  }
  if (blockIdx.x == 0) {
    int t = threadIdx.x;
    if (t < DD) {
      float s = 0.f;
      for (int c = 0; c < 2 * DD; ++c) s = fmaf(lin1_b[c], nn1_w1[c * DD + t], s);
      cvec[t] = s;
    }
    if (t >= 128 && t < 192) stats1[t - 128] = 0.f;
    if (t >= 192) stats2[t - 192] = 0.f;
  }
}

// ---------------- single-pass scatter into fixed-stride buckets ----------------
__global__ __launch_bounds__(256) void kb_scatter(const int* __restrict__ ei,
                                                  int* __restrict__ bcursor,
                                                  int* __restrict__ tsrc,
                                                  unsigned char* __restrict__ tdst) {
  __shared__ int cnt[NB];
  __shared__ int wbase[NB];
  const int t = threadIdx.x;
  for (int i = t; i < NB; i += 256) cnt[i] = 0;
  __syncthreads();
  const int base = blockIdx.x * (256 * EPT);
  int s[EPT], d[EPT];
  #pragma unroll
  for (int i = 0; i < EPT; ++i) {
    int e = base + i * 256 + t;
    if (e < NE) {
      s[i] = ei[e];
      d[i] = ei[NE + e];
      atomicAdd(&cnt[d[i] >> 8], 1);
    } else {
      s[i] = -1; d[i] = -1;
    }
  }
  __syncthreads();
  for (int i = t; i < NB; i += 256) wbase[i] = atomicAdd(&bcursor[i], cnt[i]);
  __syncthreads();
  #pragma unroll
  for (int i = 0; i < EPT; ++i) {
    if (d[i] >= 0) {
      int bk = d[i] >> 8;
      int p = atomicAdd(&wbase[bk], 1);
      int gp = bk * BST + p;
      tsrc[gp] = s[i];
      tdst[gp] = (unsigned char)(d[i] & (NPB - 1));
    }
  }
}

// ---------------- per-bucket fine sort: rs/re + compact srcidx (bucket-strided CSR)
__global__ __launch_bounds__(256) void kb_fine(const int* __restrict__ bcursor,
                                               const int* __restrict__ tsrc,
                                               const unsigned char* __restrict__ tdst,
                                               int* __restrict__ rs, int* __restrict__ re,
                                               int* __restrict__ srcidx) {
  __shared__ int deg[NPB];
  __shared__ int cur[NPB];
  __shared__ int woff[4];
  const int b = blockIdx.x, t = threadIdx.x;
  const int beg = b * BST;
  const int end = beg + bcursor[b];
  deg[t] = 0;
  __syncthreads();
  for (int i = beg + t; i < end; i += 256) atomicAdd(&deg[tdst[i]], 1);
  __syncthreads();
  int v = deg[t];
  int lane = t & 63, wave = t >> 6;
  int inc = v;
  #pragma unroll
  for (int off = 1; off < 64; off <<= 1) {
    int u = __shfl_up(inc, off);
    if (lane >= off) inc += u;
  }
  if (lane == 63) woff[wave] = inc;
  __syncthreads();
  int wadd = 0;
  for (int w = 0; w < wave; ++w) wadd += woff[w];
  int excl = wadd + inc - v;
  int gnode = b * NPB + t;
  if (gnode < NN) {
    rs[gnode] = beg + excl;
    re[gnode] = beg + excl + v;
  }
  cur[t] = beg + excl;
  __syncthreads();
  for (int i = beg + t; i < end; i += 256) {
    int p = atomicAdd(&cur[tdst[i]], 1);
    srcidx[p] = tsrc[i];
  }
}

// ---------------- K1 v8 (MFMA, k-split): zb = bf16(x @ M + cvec)
__global__ __launch_bounds__(256) void k1_mfma(
    const float* __restrict__ x,
    const unsigned short* __restrict__ Bh,
    const float* __restrict__ cvec, unsigned short* __restrict__ zb) {
  __shared__ float part[2][64][9];
  const int tid = threadIdx.x;
  const int lane = tid & 63;
  const int w = tid >> 6;
  const int rg = w & 1;
  const int kh = w >> 1;
  const int row0 = blockIdx.x * 32 + rg * 16;
  const int g = lane >> 4;
  const int r = row0 + (lane & 15);
  const float* __restrict__ xr = x + (size_t)r * FI + g * 8;
  f32x4 acc0 = {0.f, 0.f, 0.f, 0.f};
  f32x4 acc1 = {0.f, 0.f, 0.f, 0.f};

  if (kh == 0) {
    float4 a0 = *(const float4*)&xr[0];
    float4 b0 = *(const float4*)&xr[4];
    float4 a1 = *(const float4*)&xr[32];
    float4 b1 = *(const float4*)&xr[36];
    bf16x8 f0c = *(const bf16x8*)&Bh[(size_t)lane * 8];
    bf16x8 f1c = *(const bf16x8*)&Bh[(size_t)lane * 8 + 512];
    #pragma unroll
    for (int s = 0; s < 10; ++s) {
      float4 ca = a0, cb = b0;
      a0 = a1; b0 = b1;
      if (s + 2 < 10) {
        a1 = *(const float4*)&xr[(s + 2) * 32];
        b1 = *(const float4*)&xr[(s + 2) * 32 + 4];
      }
      bf16x8 f0n, f1n;
      if (s + 1 < 10) {
        const size_t fb = ((size_t)((s + 1) * 2) * 64 + lane) * 8;
        f0n = *(const bf16x8*)&Bh[fb];
        f1n = *(const bf16x8*)&Bh[fb + 512];
      }
      bf16x8 ahi, alo;
      float cv0[8] = {ca.x, ca.y, ca.z, ca.w, cb.x, cb.y, cb.z, cb.w};
      #pragma unroll
      for (int j = 0; j < 8; ++j) {
        unsigned ub = __float_as_uint(cv0[j]);
        unsigned short h = (unsigned short)(ub >> 16);
        float hv = __uint_as_float(ub & 0xffff0000u);
        float d = cv0[j] - hv;
        ahi[j] = (short)h;
        alo[j] = (short)(__float_as_uint(d) >> 16);
      }
      acc0 = __builtin_amdgcn_mfma_f32_16x16x32_bf16(ahi, f0c, acc0, 0, 0, 0);
      acc1 = __builtin_amdgcn_mfma_f32_16x16x32_bf16(ahi, f1c, acc1, 0, 0, 0);
      acc0 = __builtin_amdgcn_mfma_f32_16x16x32_bf16(alo, f0c, acc0, 0, 0, 0);
      acc1 = __builtin_amdgcn_mfma_f32_16x16x32_bf16(alo, f1c, acc1, 0, 0, 0);
      if (s + 1 < 10) { f0c = f0n; f1c = f1n; }
    }
  } else {
    float4 a0 = *(const float4*)&xr[10 * 32];
    float4 b0 = *(const float4*)&xr[10 * 32 + 4];
    float4 a1 = *(const float4*)&xr[11 * 32];
    float4 b1 = *(const float4*)&xr[11 * 32 + 4];
    bf16x8 f0c = *(const bf16x8*)&Bh[((size_t)(10 * 2) * 64 + lane) * 8];
    bf16x8 f1c = *(const bf16x8*)&Bh[((size_t)(10 * 2) * 64 + lane) * 8 + 512];
    #pragma unroll
    for (int s = 10; s < KSTEPS; ++s) {
      float4 ca = a0, cb = b0;
      a0 = a1; b0 = b1;
      if (s + 2 < KSTEPS - 1) {
        a1 = *(const float4*)&xr[(s + 2) * 32];
        b1 = *(const float4*)&xr[(s + 2) * 32 + 4];
      } else if (s + 2 == KSTEPS - 1) {
        if (g == 3) {
          float2 tt = *(const float2*)&xr[18 * 32];   // cols 600,601
          a1 = make_float4(tt.x, tt.y, 0.f, 0.f);
          b1 = make_float4(0.f, 0.f, 0.f, 0.f);
        } else {
          a1 = *(const float4*)&xr[18 * 32];
          b1 = *(const float4*)&xr[18 * 32 + 4];
        }
      }
      bf16x8 f0n, f1n;
      if (s + 1 < KSTEPS) {
        const size_t fb = ((size_t)((s + 1) * 2) * 64 + lane) * 8;
        f0n = *(const bf16x8*)&Bh[fb];
        f1n = *(const bf16x8*)&Bh[fb + 512];
      }
      bf16x8 ahi, alo;
      float cv0[8] = {ca.x, ca.y, ca.z, ca.w, cb.x, cb.y, cb.z, cb.w};
      #pragma unroll
      for (int j = 0; j < 8; ++j) {
        unsigned ub = __float_as_uint(cv0[j]);
        unsigned short h = (unsigned short)(ub >> 16);
        float hv = __uint_as_float(ub & 0xffff0000u);
        float d = cv0[j] - hv;
        ahi[j] = (short)h;
        alo[j] = (short)(__float_as_uint(d) >> 16);
      }
      acc0 = __builtin_amdgcn_mfma_f32_16x16x32_bf16(ahi, f0c, acc0, 0, 0, 0);
      acc1 = __builtin_amdgcn_mfma_f32_16x16x32_bf16(ahi, f1c, acc1, 0, 0, 0);
      acc0 = __builtin_amdgcn_mfma_f32_16x16x32_bf16(alo, f0c, acc0, 0, 0, 0);
      acc1 = __builtin_amdgcn_mfma_f32_16x16x32_bf16(alo, f1c, acc1, 0, 0, 0);
      if (s + 1 < KSTEPS) { f0c = f0n; f1c = f1n; }
    }
    #pragma unroll
    for (int j = 0; j < 4; ++j) {
      part[rg][lane][j] = acc0[j];
      part[rg][lane][4 + j] = acc1[j];
    }
  }
  __syncthreads();
  if (kh == 0) {
    const int c0 = lane & 15;
    const float cva = cvec[c0], cvb = cvec[16 + c0];
    #pragma unroll
    for (int j = 0; j < 4; ++j) {
      float v0 = acc0[j] + part[rg][lane][j] + cva;
      float v1 = acc1[j] + part[rg][lane][4 + j] + cvb;
      int rr = row0 + g * 4 + j;
      zb[(size_t)rr * DD + c0] = f2b(v0);
      zb[(size_t)rr * DD + 16 + c0] = f2b(v1);
    }
  }
}

// ---------------- gather helper (register, 4 lanes/node, depth-8)
__device__ __forceinline__ void gather8(const unsigned short* __restrict__ srcb,
                                        const int* __restrict__ srcidx,
                                        int beg, int end, int q, float* a) {
  int i = beg;
  for (; i + 8 <= end; i += 8) {
    uint4 v[8];
    #pragma unroll
    for (int j = 0; j < 8; ++j) v[j] = *(const uint4*)&srcb[(size_t)srcidx[i + j] * DD + q * 8];
    #pragma unroll
    for (int j = 0; j < 8; ++j) {
      a[0] += blo(v[j].x); a[1] += bhi(v[j].x);
      a[2] += blo(v[j].y); a[3] += bhi(v[j].y);
      a[4] += blo(v[j].z); a[5] += bhi(v[j].z);
      a[6] += blo(v[j].w); a[7] += bhi(v[j].w);
    }
  }
  for (; i + 4 <= end; i += 4) {
    uint4 v[4];
    #pragma unroll
    for (int j = 0; j < 4; ++j) v[j] = *(const uint4*)&srcb[(size_t)srcidx[i + j] * DD + q * 8];
    #pragma unroll
    for (int j = 0; j < 4; ++j) {
      a[0] += blo(v[j].x); a[1] += bhi(v[j].x);
      a[2] += blo(v[j].y); a[3] += bhi(v[j].y);
      a[4] += blo(v[j].z); a[5] += bhi(v[j].z);
      a[6] += blo(v[j].w); a[7] += bhi(v[j].w);
    }
  }
  for (; i < end; ++i) {
    uint4 v0 = *(const uint4*)&srcb[(size_t)srcidx[i] * DD + q * 8];
    a[0] += blo(v0.x); a[1] += bhi(v0.x);
    a[2] += blo(v0.y); a[3] += bhi(v0.y);
    a[4] += blo(v0.z); a[5] += bhi(v0.z);
    a[6] += blo(v0.w); a[7] += bhi(v0.w);
  }
}

// ---------------- K3 fused (barrier-free after gather): g1b = bf16(mlp1(zb_self + sum zb_nbrs)) ; stats
// 4 lanes/node; weights staged + ONE barrier BEFORE gather; MLP input exchange via __shfl
// (lane (lane&0x3c)|(k>>3) holds channel k in a[k&7]); stats via shfl_xor; end barrier only for stats combine.
__global__ __launch_bounds__(256) void k3_fused(
    const unsigned short* __restrict__ zb,
    const int* __restrict__ rsA, const int* __restrict__ reA,
    const int* __restrict__ srcidx,
    const float* __restrict__ w2, const float* __restrict__ b1, const float* __restrict__ b2,
    unsigned short* __restrict__ g1b, float* __restrict__ stats) {
  __shared__ float w2s[DD * DD];
  __shared__ float b1s[DD], b2s[DD];
  __shared__ float ps[4][2 * DD];
  const int tid = threadIdx.x;
  const int lane = tid & 63;
  const int q = tid & 3;
  const int n = blockIdx.x * 64 + (tid >> 2);
  const bool valid = n < NN;
  for (int i = tid; i < DD * DD; i += 256) w2s[i] = w2[i];
  if (tid < DD) b1s[tid] = b1[tid];
  else if (tid < 2 * DD) b2s[tid - DD] = b2[tid - DD];
  __syncthreads();   // weights visible; all waves still aligned (no gather yet)

  float a[8] = {};
  if (valid) {
    uint4 v = *(const uint4*)&zb[(size_t)n * DD + q * 8];   // self row
    a[0] = blo(v.x); a[1] = bhi(v.x); a[2] = blo(v.y); a[3] = bhi(v.y);
    a[4] = blo(v.z); a[5] = bhi(v.z); a[6] = blo(v.w); a[7] = bhi(v.w);
    gather8(zb, srcidx, rsA[n], reA[n], q, a);
  }
  // MLP1 (wave-internal, no barrier): g = relu(u + b1) @ w2 + b2
  float g[8];
  #pragma unroll
  for (int j = 0; j < 8; ++j) g[j] = b2s[q * 8 + j];
  #pragma unroll
  for (int k = 0; k < DD; ++k) {
    float uv = __shfl(a[k & 7], (lane & 0x3c) | (k >> 3), 64);
    float tv = fmaxf(uv + b1s[k], 0.f);
    #pragma unroll
    for (int j = 0; j < 8; ++j) g[j] = fmaf(tv, w2s[k * DD + q * 8 + j], g[j]);
  }
  // stats over the wave's 16 nodes (xor on node bits 2..5 of lane)
  float sv[8], sq[8];
  #pragma unroll
  for (int j = 0; j < 8; ++j) { sv[j] = valid ? g[j] : 0.f; sq[j] = sv[j] * sv[j]; }
  #pragma unroll
  for (int j = 0; j < 8; ++j) {
    #pragma unroll
    for (int off = 4; off < 64; off <<= 1) { sv[j] += __shfl_xor(sv[j], off); sq[j] += __shfl_xor(sq[j], off); }
  }
  if (lane < 4) {
    int w = tid >> 6;
    #pragma unroll
    for (int j = 0; j < 8; ++j) { ps[w][q * 8 + j] = sv[j]; ps[w][DD + q * 8 + j] = sq[j]; }
  }
  // output BEFORE the stats barrier
  if (valid) {
    unsigned u0 = ((unsigned)f2b(g[1]) << 16) | f2b(g[0]);
    unsigned u1 = ((unsigned)f2b(g[3]) << 16) | f2b(g[2]);
    unsigned u2 = ((unsigned)f2b(g[5]) << 16) | f2b(g[4]);
    unsigned u3 = ((unsigned)f2b(g[7]) << 16) | f2b(g[6]);
    *(uint4*)&g1b[(size_t)n * DD + q * 8] = make_uint4(u0, u1, u2, u3);
  }
  __syncthreads();
  if (tid < 2 * DD)
    atomAdd(&stats[tid], ps[0][tid] + ps[1][tid] + ps[2][tid] + ps[3][tid]);
}

// ---------------- K6 fused: BN1 inline from stats1 ; u = (self+sum)*rs + (1+deg)*sh ;
// g2 = relu(u@w1+b1)@w2+b2 ; stats2. Same barrier-free structure.
__global__ __launch_bounds__(256) void k6_fused(
    const unsigned short* __restrict__ g1b,
    const int* __restrict__ rsA, const int* __restrict__ reA,
    const int* __restrict__ srcidx,
    const float* __restrict__ stats1, const float* __restrict__ bn1_g, const float* __restrict__ bn1_b,
    const float* __restrict__ w1, const float* __restrict__ b1,
    const float* __restrict__ w2, const float* __restrict__ b2,
    float* __restrict__ g2, float* __restrict__ stats) {
  __shared__ float w1s[DD * DD];
  __shared__ float w2s[DD * DD];
  __shared__ float bns[2 * DD];
  __shared__ float b1s[DD], b2s[DD];
  __shared__ float ps[4][2 * DD];
  const int tid = threadIdx.x;
  const int lane = tid & 63;
  const int q = tid & 3;
  const int n = blockIdx.x * 64 + (tid >> 2);
  const bool valid = n < NN;
  for (int i = tid; i < DD * DD; i += 256) { w1s[i] = w1[i]; w2s[i] = w2[i]; }
  if (tid < DD) {
    float mu = stats1[tid] * (1.f / NN);
    float var = stats1[DD + tid] * (1.f / NN) - mu * mu;
    float rsv = rsqrtf(var + BN_EPS) * bn1_g[tid];
    bns[tid] = rsv;
    bns[DD + tid] = bn1_b[tid] - mu * rsv;
    b1s[tid] = b1[tid];
  } else if (tid < 2 * DD) {
    b2s[tid - DD] = b2[tid - DD];
  }
  __syncthreads();   // weights/BN staged before gather

  float a[8] = {};
  float degp1 = 1.f;
  if (valid) {
    uint4 v = *(const uint4*)&g1b[(size_t)n * DD + q * 8];
    a[0] = blo(v.x); a[1] = bhi(v.x); a[2] = blo(v.y); a[3] = bhi(v.y);
    a[4] = blo(v.z); a[5] = bhi(v.z); a[6] = blo(v.w); a[7] = bhi(v.w);
    int beg = rsA[n], end = reA[n];
    degp1 = (float)(end - beg + 1);
    gather8(g1b, srcidx, beg, end, q, a);
  }
  // layer 1: t1 = relu((a*rs + degp1*sh) @ w1 + b1), cols q*8..q*8+7
  float t1[8];
  #pragma unroll
  for (int j = 0; j < 8; ++j) t1[j] = b1s[q * 8 + j];
  #pragma unroll
  for (int k = 0; k < DD; ++k) {
    float uv = __shfl(a[k & 7], (lane & 0x3c) | (k >> 3), 64);
    float u = fmaf(uv, bns[k], degp1 * bns[DD + k]);
    #pragma unroll
    for (int j = 0; j < 8; ++j) t1[j] = fmaf(u, w1s[k * DD + q * 8 + j], t1[j]);
  }
  #pragma unroll
  for (int j = 0; j < 8; ++j) t1[j] = fmaxf(t1[j], 0.f);
  // layer 2: g = t1 @ w2 + b2 (second shuffle exchange)
  float g[8];
  #pragma unroll
  for (int j = 0; j < 8; ++j) g[j] = b2s[q * 8 + j];
  #pragma unroll
  for (int k = 0; k < DD; ++k) {
    float tv = __shfl(t1[k & 7], (lane & 0x3c) | (k >> 3), 64);
    #pragma unroll
    for (int j = 0; j < 8; ++j) g[j] = fmaf(tv, w2s[k * DD + q * 8 + j], g[j]);
  }
  // stats2
  float sv[8], sq[8];
  #pragma unroll
  for (int j = 0; j < 8; ++j) { sv[j] = valid ? g[j] : 0.f; sq[j] = sv[j] * sv[j]; }
  #pragma unroll
  for (int j = 0; j < 8; ++j) {
    #pragma unroll
    for (int off = 4; off < 64; off <<= 1) { sv[j] += __shfl_xor(sv[j], off); sq[j] += __shfl_xor(sq[j], off); }
  }
  if (lane < 4) {
    int w = tid >> 6;
    #pragma unroll
    for (int j = 0; j < 8; ++j) { ps[w][q * 8 + j] = sv[j]; ps[w][DD + q * 8 + j] = sq[j]; }
  }
  if (valid) {
    float* gp = &g2[(size_t)n * DD + q * 8];
    *(float4*)&gp[0] = make_float4(g[0], g[1], g[2], g[3]);
    *(float4*)&gp[4] = make_float4(g[4], g[5], g[6], g[7]);
  }
  __syncthreads();
  if (tid < 2 * DD)
    atomAdd(&stats[tid], ps[0][tid] + ps[1][tid] + ps[2][tid] + ps[3][tid]);
}

// ---------------- K7: out = relu(bn2(g2)@fc1+b)@fc2+b
__global__ __launch_bounds__(256) void k7_head(
    const float* __restrict__ g2, const float* __restrict__ stats2,
    const float* __restrict__ bn2_g, const float* __restrict__ bn2_b,
    const float* __restrict__ fc1_w, const float* __restrict__ fc1_b,
    const float* __restrict__ fc2_w, const float* __restrict__ fc2_b,
    float* __restrict__ out) {
  __shared__ float buf[256 * 42];
  __shared__ float fc1s[DD * DD];
  __shared__ float fc2s[DD * CC];
  __shared__ float mu2[DD], rsg2[DD], bet2[DD];
  const int tid = threadIdx.x;
  const int n0 = blockIdx.x * 256;
  if (tid < DD) {
    float mu = stats2[tid] * (1.f / NN);
    float var = stats2[DD + tid] * (1.f / NN) - mu * mu;
    mu2[tid] = mu;
    rsg2[tid] = rsqrtf(var + BN_EPS) * bn2_g[tid];
    bet2[tid] = bn2_b[tid];
  }
  for (int i = tid; i < DD * DD; i += 256) fc1s[i] = fc1_w[i];
  for (int i = tid; i < DD * CC; i += 256) fc2s[i] = fc2_w[i];
  __syncthreads();
  #pragma unroll
  for (int i = 0; i < 32; ++i) {
    int l = tid + i * 256;
    int r = l >> 5, c = l & 31;
    float v = 0.f;
    if (n0 + r < NN) v = (g2[(size_t)(n0 + r) * DD + c] - mu2[c]) * rsg2[c] + bet2[c];
    buf[r * 33 + c] = v;
  }
  __syncthreads();
  float t[DD];
  #pragma unroll
  for (int j = 0; j < DD; ++j) t[j] = fc1_b[j];
  #pragma unroll
  for (int k = 0; k < DD; ++k) {
    float uv = buf[tid * 33 + k];
    #pragma unroll
    for (int j = 0; j < DD; ++j) t[j] = fmaf(uv, fc1s[k * DD + j], t[j]);
  }
  #pragma unroll
  for (int j = 0; j < DD; ++j) t[j] = fmaxf(t[j], 0.f);
  float o[CC];
  #pragma unroll
  for (int j = 0; j < CC; ++j) o[j] = fc2_b[j];
  #pragma unroll
  for (int k = 0; k < DD; ++k) {
    float tv = t[k];
    #pragma unroll
    for (int j = 0; j < CC; ++j) o[j] = fmaf(tv, fc2s[k * CC + j], o[j]);
  }
  __syncthreads();
  #pragma unroll
  for (int j = 0; j < CC; ++j) buf[tid * 42 + j] = o[j];
  __syncthreads();
  for (int i = 0; i < CC; ++i) {
    int l = tid + i * 256;
    int r = l / CC, c = l % CC;
    if (n0 + r < NN) out[(size_t)(n0 + r) * CC + c] = buf[r * 42 + c];
  }
}

extern "C" void kernel_launch(void* const* d_in, const int* in_sizes, int n_in,
                              void* d_out, int out_size, void* d_ws, size_t ws_size,
                              hipStream_t stream) {
  const float* x      = (const float*)d_in[0];
  const int*   ei     = (const int*)d_in[1];
  const float* lin1_w = (const float*)d_in[2];
  const float* lin1_b = (const float*)d_in[3];
  const float* nn1_w1 = (const float*)d_in[4];
  const float* nn1_b1 = (const float*)d_in[5];
  const float* nn1_w2 = (const float*)d_in[6];
  const float* nn1_b2 = (const float*)d_in[7];
  const float* bn1_g  = (const float*)d_in[8];
  const float* bn1_b  = (const float*)d_in[9];
  const float* nn2_w1 = (const float*)d_in[10];
  const float* nn2_b1 = (const float*)d_in[11];
  const float* nn2_w2 = (const float*)d_in[12];
  const float* nn2_b2 = (const float*)d_in[13];
  const float* bn2_g  = (const float*)d_in[14];
  const float* bn2_b  = (const float*)d_in[15];
  const float* fc1_w  = (const float*)d_in[16];
  const float* fc1_b  = (const float*)d_in[17];
  const float* fc2_w  = (const float*)d_in[18];
  const float* fc2_b  = (const float*)d_in[19];
  float* out = (float*)d_out;

  float* ws = (float*)d_ws;
  size_t nd = (size_t)NN * DD;
  float* A      = ws;            // g2 (f32)
  float* B      = ws + nd;       // g1b (bf16, uses half the slot)
  float* cvec   = ws + 2 * nd;
  float* stats1 = cvec + 32;
  float* stats2 = stats1 + 64;
  unsigned short* Bh = (unsigned short*)(stats2 + 64);      // 19456 shorts (38 KB)
  int*   rsA      = (int*)(Bh + KSTEPS * 2 * 64 * 8);       // NN
  int*   reA      = rsA + NN;                               // NN
  int*   srcidx   = reA + NN;                               // NB*BST
  int*   tsrc     = srcidx + (size_t)NB * BST;              // NB*BST ints; dead after kb_fine
  unsigned char* tdst = (unsigned char*)(tsrc + (size_t)NB * BST);  // NB*BST bytes
  int*   bcursor  = (int*)(tdst + (size_t)NB * BST);        // NB
  unsigned short* zb  = (unsigned short*)tsrc;              // aliases dead tsrc (7.2MB >= 6.4MB)
  unsigned short* g1b = (unsigned short*)B;                 // separate buffer (cross-block reads)

  // single-pass bucketed CSR build
  hipMemsetAsync(bcursor, 0, NB * sizeof(int), stream);
  kb_scatter<<<SCB, 256, 0, stream>>>(ei, bcursor, tsrc, tdst);
  kb_fine<<<NB, 256, 0, stream>>>(bcursor, tsrc, tdst, rsA, reA, srcidx);

  k0_prep<<<(KSTEPS * 32 * 32 + 255) / 256, 256, 0, stream>>>(
      lin1_w, lin1_b, nn1_w1, Bh, cvec, stats1, stats2);
  k1_mfma<<<NN / 32, 256, 0, stream>>>(x, Bh, cvec, zb);
  k3_fused<<<(NN + 63) / 64, 256, 0, stream>>>(zb, rsA, reA, srcidx,
                                               nn1_w2, nn1_b1, nn1_b2, g1b, stats1);
  k6_fused<<<(NN + 63) / 64, 256, 0, stream>>>(g1b, rsA, reA, srcidx,
                                               stats1, bn1_g, bn1_b,
                                               nn2_w1, nn2_b1, nn2_w2, nn2_b2, A, stats2);
  k7_head<<<(NN + 255) / 256, 256, 0, stream>>>(A, stats2, bn2_g, bn2_b, fc1_w, fc1_b, fc2_w, fc2_b, out);
}

// Round 16
// 240.663 us; speedup vs baseline: 1.1820x; 1.0573x over previous
//
#include <hip/hip_runtime.h>
#include <cstdint>

#define NN 100000
#define NE 1600000
#define FI 602
#define DD 32
#define CC 41
#define BN_EPS 1e-5f
#define KSTEPS 19                 // 19*32 = 608 >= 602 (k-padded with zeros)

// single-pass bucketed CSR build
#define NPB 256                   // nodes per bucket (dst >> 8)
#define NB 391                    // ceil(NN/NPB)
#define BST 4608                  // fixed bucket stride (mean 4096, sigma 64 -> 8-sigma margin)
#define EPT 13                    // edges per thread in scatter
#define SCB 481                   // ceil(NE / (256*EPT))
#define K0B 76                    // ceil(KSTEPS*32*32 / 256)

typedef __attribute__((ext_vector_type(8))) short bf16x8;
typedef __attribute__((ext_vector_type(4))) float f32x4;

__device__ __forceinline__ void atomAdd(float* p, float v) {
#ifdef __HIP_PLATFORM_AMD__
  unsafeAtomicAdd(p, v);
#else
  atomicAdd(p, v);
#endif
}

// round-to-nearest-even f32 -> bf16 bits
__device__ __forceinline__ unsigned short f2b(float f) {
  unsigned u = __float_as_uint(f);
  unsigned r = (u + 0x7fffu + ((u >> 16) & 1u)) >> 16;
  return (unsigned short)r;
}
__device__ __forceinline__ float blo(unsigned u) { return __uint_as_float(u << 16); }
__device__ __forceinline__ float bhi(unsigned u) { return __uint_as_float(u & 0xffff0000u); }

// ---------------- K0S: blocks [0,SCB) = edge scatter ; blocks [SCB,SCB+K0B) = weight prep
__global__ __launch_bounds__(256) void k0s(
    const int* __restrict__ ei, int* __restrict__ bcursor,
    int* __restrict__ tsrc, unsigned char* __restrict__ tdst,
    const float* __restrict__ lin1_w, const float* __restrict__ lin1_b,
    const float* __restrict__ nn1_w1,
    unsigned short* __restrict__ Bh, float* __restrict__ cvec,
    float* __restrict__ stats1, float* __restrict__ stats2) {
  __shared__ int cnt[NB];
  __shared__ int wbase[NB];
  const int t = threadIdx.x;
  const int blk = blockIdx.x;
  if (blk < SCB) {
    // ---- scatter into fixed-stride buckets
    for (int i = t; i < NB; i += 256) cnt[i] = 0;
    __syncthreads();
    const int base = blk * (256 * EPT);
    int s[EPT], d[EPT];
    #pragma unroll
    for (int i = 0; i < EPT; ++i) {
      int e = base + i * 256 + t;
      if (e < NE) {
        s[i] = ei[e];
        d[i] = ei[NE + e];
        atomicAdd(&cnt[d[i] >> 8], 1);
      } else {
        s[i] = -1; d[i] = -1;
      }
    }
    __syncthreads();
    for (int i = t; i < NB; i += 256) wbase[i] = atomicAdd(&bcursor[i], cnt[i]);
    __syncthreads();
    #pragma unroll
    for (int i = 0; i < EPT; ++i) {
      if (d[i] >= 0) {
        int bk = d[i] >> 8;
        int p = atomicAdd(&wbase[bk], 1);
        int gp = bk * BST + p;
        tsrc[gp] = s[i];
        tdst[gp] = (unsigned char)(d[i] & (NPB - 1));
      }
    }
  } else {
    // ---- M = lin1_w @ nn1_w1 as MFMA B-fragments (single RNE bf16) ; cvec ; zero stats
    int o = (blk - SCB) * 256 + t;
    if (o < KSTEPS * 32 * 32) {
      int k = o >> 5, j = o & 31;
      float sm = 0.f;
      if (k < FI) {
        #pragma unroll 4
        for (int c = 0; c < 2 * DD; ++c) sm = fmaf(lin1_w[k * (2 * DD) + c], nn1_w1[c * DD + j], sm);
      }
      int st = k >> 5, kk = k & 31, g = kk >> 3, jj = kk & 7;
      int h = j >> 4, lane = g * 16 + (j & 15);
      int idx = ((st * 2 + h) * 64 + lane) * 8 + jj;
      Bh[idx] = f2b(sm);
    }
    if (blk == SCB) {
      if (t < DD) {
        float sm = 0.f;
        for (int c = 0; c < 2 * DD; ++c) sm = fmaf(lin1_b[c], nn1_w1[c * DD + t], sm);
        cvec[t] = sm;
      }
      if (t >= 128 && t < 192) stats1[t - 128] = 0.f;
      if (t >= 192) stats2[t - 192] = 0.f;
    }
  }
}

// ---------------- per-bucket fine sort: rs/re + compact srcidx (bucket-strided CSR)
__global__ __launch_bounds__(256) void kb_fine(const int* __restrict__ bcursor,
                                               const int* __restrict__ tsrc,
                                               const unsigned char* __restrict__ tdst,
                                               int* __restrict__ rs, int* __restrict__ re,
                                               int* __restrict__ srcidx) {
  __shared__ int deg[NPB];
  __shared__ int cur[NPB];
  __shared__ int woff[4];
  const int b = blockIdx.x, t = threadIdx.x;
  const int beg = b * BST;
  const int end = beg + bcursor[b];
  deg[t] = 0;
  __syncthreads();
  for (int i = beg + t; i < end; i += 256) atomicAdd(&deg[tdst[i]], 1);
  __syncthreads();
  int v = deg[t];
  int lane = t & 63, wave = t >> 6;
  int inc = v;
  #pragma unroll
  for (int off = 1; off < 64; off <<= 1) {
    int u = __shfl_up(inc, off);
    if (lane >= off) inc += u;
  }
  if (lane == 63) woff[wave] = inc;
  __syncthreads();
  int wadd = 0;
  for (int w = 0; w < wave; ++w) wadd += woff[w];
  int excl = wadd + inc - v;
  int gnode = b * NPB + t;
  if (gnode < NN) {
    rs[gnode] = beg + excl;
    re[gnode] = beg + excl + v;
  }
  cur[t] = beg + excl;
  __syncthreads();
  for (int i = beg + t; i < end; i += 256) {
    int p = atomicAdd(&cur[tdst[i]], 1);
    srcidx[p] = tsrc[i];
  }
}

// ---------------- K1 v8 (MFMA, k-split): zb = bf16(x @ M + cvec)
__global__ __launch_bounds__(256) void k1_mfma(
    const float* __restrict__ x,
    const unsigned short* __restrict__ Bh,
    const float* __restrict__ cvec, unsigned short* __restrict__ zb) {
  __shared__ float part[2][64][9];
  const int tid = threadIdx.x;
  const int lane = tid & 63;
  const int w = tid >> 6;
  const int rg = w & 1;
  const int kh = w >> 1;
  const int row0 = blockIdx.x * 32 + rg * 16;
  const int g = lane >> 4;
  const int r = row0 + (lane & 15);
  const float* __restrict__ xr = x + (size_t)r * FI + g * 8;
  f32x4 acc0 = {0.f, 0.f, 0.f, 0.f};
  f32x4 acc1 = {0.f, 0.f, 0.f, 0.f};

  if (kh == 0) {
    float4 a0 = *(const float4*)&xr[0];
    float4 b0 = *(const float4*)&xr[4];
    float4 a1 = *(const float4*)&xr[32];
    float4 b1 = *(const float4*)&xr[36];
    bf16x8 f0c = *(const bf16x8*)&Bh[(size_t)lane * 8];
    bf16x8 f1c = *(const bf16x8*)&Bh[(size_t)lane * 8 + 512];
    #pragma unroll
    for (int s = 0; s < 10; ++s) {
      float4 ca = a0, cb = b0;
      a0 = a1; b0 = b1;
      if (s + 2 < 10) {
        a1 = *(const float4*)&xr[(s + 2) * 32];
        b1 = *(const float4*)&xr[(s + 2) * 32 + 4];
      }
      bf16x8 f0n, f1n;
      if (s + 1 < 10) {
        const size_t fb = ((size_t)((s + 1) * 2) * 64 + lane) * 8;
        f0n = *(const bf16x8*)&Bh[fb];
        f1n = *(const bf16x8*)&Bh[fb + 512];
      }
      bf16x8 ahi, alo;
      float cv0[8] = {ca.x, ca.y, ca.z, ca.w, cb.x, cb.y, cb.z, cb.w};
      #pragma unroll
      for (int j = 0; j < 8; ++j) {
        unsigned ub = __float_as_uint(cv0[j]);
        unsigned short h = (unsigned short)(ub >> 16);
        float hv = __uint_as_float(ub & 0xffff0000u);
        float d = cv0[j] - hv;
        ahi[j] = (short)h;
        alo[j] = (short)(__float_as_uint(d) >> 16);
      }
      acc0 = __builtin_amdgcn_mfma_f32_16x16x32_bf16(ahi, f0c, acc0, 0, 0, 0);
      acc1 = __builtin_amdgcn_mfma_f32_16x16x32_bf16(ahi, f1c, acc1, 0, 0, 0);
      acc0 = __builtin_amdgcn_mfma_f32_16x16x32_bf16(alo, f0c, acc0, 0, 0, 0);
      acc1 = __builtin_amdgcn_mfma_f32_16x16x32_bf16(alo, f1c, acc1, 0, 0, 0);
      if (s + 1 < 10) { f0c = f0n; f1c = f1n; }
    }
  } else {
    float4 a0 = *(const float4*)&xr[10 * 32];
    float4 b0 = *(const float4*)&xr[10 * 32 + 4];
    float4 a1 = *(const float4*)&xr[11 * 32];
    float4 b1 = *(const float4*)&xr[11 * 32 + 4];
    bf16x8 f0c = *(const bf16x8*)&Bh[((size_t)(10 * 2) * 64 + lane) * 8];
    bf16x8 f1c = *(const bf16x8*)&Bh[((size_t)(10 * 2) * 64 + lane) * 8 + 512];
    #pragma unroll
    for (int s = 10; s < KSTEPS; ++s) {
      float4 ca = a0, cb = b0;
      a0 = a1; b0 = b1;
      if (s + 2 < KSTEPS - 1) {
        a1 = *(const float4*)&xr[(s + 2) * 32];
        b1 = *(const float4*)&xr[(s + 2) * 32 + 4];
      } else if (s + 2 == KSTEPS - 1) {
        if (g == 3) {
          float2 tt = *(const float2*)&xr[18 * 32];   // cols 600,601
          a1 = make_float4(tt.x, tt.y, 0.f, 0.f);
          b1 = make_float4(0.f, 0.f, 0.f, 0.f);
        } else {
          a1 = *(const float4*)&xr[18 * 32];
          b1 = *(const float4*)&xr[18 * 32 + 4];
        }
      }
      bf16x8 f0n, f1n;
      if (s + 1 < KSTEPS) {
        const size_t fb = ((size_t)((s + 1) * 2) * 64 + lane) * 8;
        f0n = *(const bf16x8*)&Bh[fb];
        f1n = *(const bf16x8*)&Bh[fb + 512];
      }
      bf16x8 ahi, alo;
      float cv0[8] = {ca.x, ca.y, ca.z, ca.w, cb.x, cb.y, cb.z, cb.w};
      #pragma unroll
      for (int j = 0; j < 8; ++j) {
        unsigned ub = __float_as_uint(cv0[j]);
        unsigned short h = (unsigned short)(ub >> 16);
        float hv = __uint_as_float(ub & 0xffff0000u);
        float d = cv0[j] - hv;
        ahi[j] = (short)h;
        alo[j] = (short)(__float_as_uint(d) >> 16);
      }
      acc0 = __builtin_amdgcn_mfma_f32_16x16x32_bf16(ahi, f0c, acc0, 0, 0, 0);
      acc1 = __builtin_amdgcn_mfma_f32_16x16x32_bf16(ahi, f1c, acc1, 0, 0, 0);
      acc0 = __builtin_amdgcn_mfma_f32_16x16x32_bf16(alo, f0c, acc0, 0, 0, 0);
      acc1 = __builtin_amdgcn_mfma_f32_16x16x32_bf16(alo, f1c, acc1, 0, 0, 0);
      if (s + 1 < KSTEPS) { f0c = f0n; f1c = f1n; }
    }
    #pragma unroll
    for (int j = 0; j < 4; ++j) {
      part[rg][lane][j] = acc0[j];
      part[rg][lane][4 + j] = acc1[j];
    }
  }
  __syncthreads();
  if (kh == 0) {
    const int c0 = lane & 15;
    const float cva = cvec[c0], cvb = cvec[16 + c0];
    #pragma unroll
    for (int j = 0; j < 4; ++j) {
      float v0 = acc0[j] + part[rg][lane][j] + cva;
      float v1 = acc1[j] + part[rg][lane][4 + j] + cvb;
      int rr = row0 + g * 4 + j;
      zb[(size_t)rr * DD + c0] = f2b(v0);
      zb[(size_t)rr * DD + 16 + c0] = f2b(v1);
    }
  }
}

// ---------------- gather helper (register, 4 lanes/node, depth-12)
__device__ __forceinline__ void gather12(const unsigned short* __restrict__ srcb,
                                         const int* __restrict__ srcidx,
                                         int beg, int end, int q, float* a) {
  int i = beg;
  for (; i + 12 <= end; i += 12) {
    uint4 v[12];
    #pragma unroll
    for (int j = 0; j < 12; ++j) v[j] = *(const uint4*)&srcb[(size_t)srcidx[i + j] * DD + q * 8];
    #pragma unroll
    for (int j = 0; j < 12; ++j) {
      a[0] += blo(v[j].x); a[1] += bhi(v[j].x);
      a[2] += blo(v[j].y); a[3] += bhi(v[j].y);
      a[4] += blo(v[j].z); a[5] += bhi(v[j].z);
      a[6] += blo(v[j].w); a[7] += bhi(v[j].w);
    }
  }
  for (; i + 4 <= end; i += 4) {
    uint4 v[4];
    #pragma unroll
    for (int j = 0; j < 4; ++j) v[j] = *(const uint4*)&srcb[(size_t)srcidx[i + j] * DD + q * 8];
    #pragma unroll
    for (int j = 0; j < 4; ++j) {
      a[0] += blo(v[j].x); a[1] += bhi(v[j].x);
      a[2] += blo(v[j].y); a[3] += bhi(v[j].y);
      a[4] += blo(v[j].z); a[5] += bhi(v[j].z);
      a[6] += blo(v[j].w); a[7] += bhi(v[j].w);
    }
  }
  for (; i < end; ++i) {
    uint4 v0 = *(const uint4*)&srcb[(size_t)srcidx[i] * DD + q * 8];
    a[0] += blo(v0.x); a[1] += bhi(v0.x);
    a[2] += blo(v0.y); a[3] += bhi(v0.y);
    a[4] += blo(v0.z); a[5] += bhi(v0.z);
    a[6] += blo(v0.w); a[7] += bhi(v0.w);
  }
}

// ---------------- K3 fused (barrier-free after gather): g1b = bf16(mlp1(zb_self + sum zb_nbrs)) ; stats
__global__ __launch_bounds__(256) void k3_fused(
    const unsigned short* __restrict__ zb,
    const int* __restrict__ rsA, const int* __restrict__ reA,
    const int* __restrict__ srcidx,
    const float* __restrict__ w2, const float* __restrict__ b1, const float* __restrict__ b2,
    unsigned short* __restrict__ g1b, float* __restrict__ stats) {
  __shared__ float w2s[DD * DD];
  __shared__ float b1s[DD], b2s[DD];
  __shared__ float ps[4][2 * DD];
  const int tid = threadIdx.x;
  const int lane = tid & 63;
  const int q = tid & 3;
  const int n = blockIdx.x * 64 + (tid >> 2);
  const bool valid = n < NN;
  for (int i = tid; i < DD * DD; i += 256) w2s[i] = w2[i];
  if (tid < DD) b1s[tid] = b1[tid];
  else if (tid < 2 * DD) b2s[tid - DD] = b2[tid - DD];
  __syncthreads();   // weights visible; all waves still aligned (no gather yet)

  float a[8] = {};
  if (valid) {
    uint4 v = *(const uint4*)&zb[(size_t)n * DD + q * 8];   // self row
    a[0] = blo(v.x); a[1] = bhi(v.x); a[2] = blo(v.y); a[3] = bhi(v.y);
    a[4] = blo(v.z); a[5] = bhi(v.z); a[6] = blo(v.w); a[7] = bhi(v.w);
    gather12(zb, srcidx, rsA[n], reA[n], q, a);
  }
  // MLP1 (wave-internal): g = relu(u + b1) @ w2 + b2
  float g[8];
  #pragma unroll
  for (int j = 0; j < 8; ++j) g[j] = b2s[q * 8 + j];
  #pragma unroll
  for (int k = 0; k < DD; ++k) {
    float uv = __shfl(a[k & 7], (lane & 0x3c) | (k >> 3), 64);
    float tv = fmaxf(uv + b1s[k], 0.f);
    #pragma unroll
    for (int j = 0; j < 8; ++j) g[j] = fmaf(tv, w2s[k * DD + q * 8 + j], g[j]);
  }
  // stats over the wave's 16 nodes
  float sv[8], sq[8];
  #pragma unroll
  for (int j = 0; j < 8; ++j) { sv[j] = valid ? g[j] : 0.f; sq[j] = sv[j] * sv[j]; }
  #pragma unroll
  for (int j = 0; j < 8; ++j) {
    #pragma unroll
    for (int off = 4; off < 64; off <<= 1) { sv[j] += __shfl_xor(sv[j], off); sq[j] += __shfl_xor(sq[j], off); }
  }
  if (lane < 4) {
    int w = tid >> 6;
    #pragma unroll
    for (int j = 0; j < 8; ++j) { ps[w][q * 8 + j] = sv[j]; ps[w][DD + q * 8 + j] = sq[j]; }
  }
  if (valid) {
    unsigned u0 = ((unsigned)f2b(g[1]) << 16) | f2b(g[0]);
    unsigned u1 = ((unsigned)f2b(g[3]) << 16) | f2b(g[2]);
    unsigned u2 = ((unsigned)f2b(g[5]) << 16) | f2b(g[4]);
    unsigned u3 = ((unsigned)f2b(g[7]) << 16) | f2b(g[6]);
    *(uint4*)&g1b[(size_t)n * DD + q * 8] = make_uint4(u0, u1, u2, u3);
  }
  __syncthreads();
  if (tid < 2 * DD)
    atomAdd(&stats[tid], ps[0][tid] + ps[1][tid] + ps[2][tid] + ps[3][tid]);
}

// ---------------- K6 fused: BN1 inline ; u = (self+sum)*rs + (1+deg)*sh ; g2b = bf16(mlp2(u)) ; stats2
__global__ __launch_bounds__(256) void k6_fused(
    const unsigned short* __restrict__ g1b,
    const int* __restrict__ rsA, const int* __restrict__ reA,
    const int* __restrict__ srcidx,
    const float* __restrict__ stats1, const float* __restrict__ bn1_g, const float* __restrict__ bn1_b,
    const float* __restrict__ w1, const float* __restrict__ b1,
    const float* __restrict__ w2, const float* __restrict__ b2,
    unsigned short* __restrict__ g2b, float* __restrict__ stats) {
  __shared__ float w1s[DD * DD];
  __shared__ float w2s[DD * DD];
  __shared__ float bns[2 * DD];
  __shared__ float b1s[DD], b2s[DD];
  __shared__ float ps[4][2 * DD];
  const int tid = threadIdx.x;
  const int lane = tid & 63;
  const int q = tid & 3;
  const int n = blockIdx.x * 64 + (tid >> 2);
  const bool valid = n < NN;
  for (int i = tid; i < DD * DD; i += 256) { w1s[i] = w1[i]; w2s[i] = w2[i]; }
  if (tid < DD) {
    float mu = stats1[tid] * (1.f / NN);
    float var = stats1[DD + tid] * (1.f / NN) - mu * mu;
    float rsv = rsqrtf(var + BN_EPS) * bn1_g[tid];
    bns[tid] = rsv;
    bns[DD + tid] = bn1_b[tid] - mu * rsv;
    b1s[tid] = b1[tid];
  } else if (tid < 2 * DD) {
    b2s[tid - DD] = b2[tid - DD];
  }
  __syncthreads();

  float a[8] = {};
  float degp1 = 1.f;
  if (valid) {
    uint4 v = *(const uint4*)&g1b[(size_t)n * DD + q * 8];
    a[0] = blo(v.x); a[1] = bhi(v.x); a[2] = blo(v.y); a[3] = bhi(v.y);
    a[4] = blo(v.z); a[5] = bhi(v.z); a[6] = blo(v.w); a[7] = bhi(v.w);
    int beg = rsA[n], end = reA[n];
    degp1 = (float)(end - beg + 1);
    gather12(g1b, srcidx, beg, end, q, a);
  }
  float t1[8];
  #pragma unroll
  for (int j = 0; j < 8; ++j) t1[j] = b1s[q * 8 + j];
  #pragma unroll
  for (int k = 0; k < DD; ++k) {
    float uv = __shfl(a[k & 7], (lane & 0x3c) | (k >> 3), 64);
    float u = fmaf(uv, bns[k], degp1 * bns[DD + k]);
    #pragma unroll
    for (int j = 0; j < 8; ++j) t1[j] = fmaf(u, w1s[k * DD + q * 8 + j], t1[j]);
  }
  #pragma unroll
  for (int j = 0; j < 8; ++j) t1[j] = fmaxf(t1[j], 0.f);
  float g[8];
  #pragma unroll
  for (int j = 0; j < 8; ++j) g[j] = b2s[q * 8 + j];
  #pragma unroll
  for (int k = 0; k < DD; ++k) {
    float tv = __shfl(t1[k & 7], (lane & 0x3c) | (k >> 3), 64);
    #pragma unroll
    for (int j = 0; j < 8; ++j) g[j] = fmaf(tv, w2s[k * DD + q * 8 + j], g[j]);
  }
  float sv[8], sq[8];
  #pragma unroll
  for (int j = 0; j < 8; ++j) { sv[j] = valid ? g[j] : 0.f; sq[j] = sv[j] * sv[j]; }
  #pragma unroll
  for (int j = 0; j < 8; ++j) {
    #pragma unroll
    for (int off = 4; off < 64; off <<= 1) { sv[j] += __shfl_xor(sv[j], off); sq[j] += __shfl_xor(sq[j], off); }
  }
  if (lane < 4) {
    int w = tid >> 6;
    #pragma unroll
    for (int j = 0; j < 8; ++j) { ps[w][q * 8 + j] = sv[j]; ps[w][DD + q * 8 + j] = sq[j]; }
  }
  if (valid) {
    unsigned u0 = ((unsigned)f2b(g[1]) << 16) | f2b(g[0]);
    unsigned u1 = ((unsigned)f2b(g[3]) << 16) | f2b(g[2]);
    unsigned u2 = ((unsigned)f2b(g[5]) << 16) | f2b(g[4]);
    unsigned u3 = ((unsigned)f2b(g[7]) << 16) | f2b(g[6]);
    *(uint4*)&g2b[(size_t)n * DD + q * 8] = make_uint4(u0, u1, u2, u3);
  }
  __syncthreads();
  if (tid < 2 * DD)
    atomAdd(&stats[tid], ps[0][tid] + ps[1][tid] + ps[2][tid] + ps[3][tid]);
}

// ---------------- K7: out = relu(bn2(g2b)@fc1+b)@fc2+b  (bf16 input)
__global__ __launch_bounds__(256) void k7_head(
    const unsigned short* __restrict__ g2b, const float* __restrict__ stats2,
    const float* __restrict__ bn2_g, const float* __restrict__ bn2_b,
    const float* __restrict__ fc1_w, const float* __restrict__ fc1_b,
    const float* __restrict__ fc2_w, const float* __restrict__ fc2_b,
    float* __restrict__ out) {
  __shared__ float buf[256 * 42];
  __shared__ float fc1s[DD * DD];
  __shared__ float fc2s[DD * CC];
  __shared__ float mu2[DD], rsg2[DD], bet2[DD];
  const int tid = threadIdx.x;
  const int n0 = blockIdx.x * 256;
  if (tid < DD) {
    float mu = stats2[tid] * (1.f / NN);
    float var = stats2[DD + tid] * (1.f / NN) - mu * mu;
    mu2[tid] = mu;
    rsg2[tid] = rsqrtf(var + BN_EPS) * bn2_g[tid];
    bet2[tid] = bn2_b[tid];
  }
  for (int i = tid; i < DD * DD; i += 256) fc1s[i] = fc1_w[i];
  for (int i = tid; i < DD * CC; i += 256) fc2s[i] = fc2_w[i];
  __syncthreads();
  #pragma unroll
  for (int i = 0; i < 16; ++i) {
    int l = tid + i * 256;
    int r = l >> 4, c2 = l & 15;
    float lo = 0.f, hi = 0.f;
    if (n0 + r < NN) {
      unsigned u = *(const unsigned*)&g2b[(size_t)(n0 + r) * DD + c2 * 2];
      lo = (blo(u) - mu2[c2 * 2]) * rsg2[c2 * 2] + bet2[c2 * 2];
      hi = (bhi(u) - mu2[c2 * 2 + 1]) * rsg2[c2 * 2 + 1] + bet2[c2 * 2 + 1];
    }
    buf[r * 33 + c2 * 2] = lo;
    buf[r * 33 + c2 * 2 + 1] = hi;
  }
  __syncthreads();
  float t[DD];
  #pragma unroll
  for (int j = 0; j < DD; ++j) t[j] = fc1_b[j];
  #pragma unroll
  for (int k = 0; k < DD; ++k) {
    float uv = buf[tid * 33 + k];
    #pragma unroll
    for (int j = 0; j < DD; ++j) t[j] = fmaf(uv, fc1s[k * DD + j], t[j]);
  }
  #pragma unroll
  for (int j = 0; j < DD; ++j) t[j] = fmaxf(t[j], 0.f);
  float o[CC];
  #pragma unroll
  for (int j = 0; j < CC; ++j) o[j] = fc2_b[j];
  #pragma unroll
  for (int k = 0; k < DD; ++k) {
    float tv = t[k];
    #pragma unroll
    for (int j = 0; j < CC; ++j) o[j] = fmaf(tv, fc2s[k * CC + j], o[j]);
  }
  __syncthreads();
  #pragma unroll
  for (int j = 0; j < CC; ++j) buf[tid * 42 + j] = o[j];
  __syncthreads();
  for (int i = 0; i < CC; ++i) {
    int l = tid + i * 256;
    int r = l / CC, c = l % CC;
    if (n0 + r < NN) out[(size_t)(n0 + r) * CC + c] = buf[r * 42 + c];
  }
}

extern "C" void kernel_launch(void* const* d_in, const int* in_sizes, int n_in,
                              void* d_out, int out_size, void* d_ws, size_t ws_size,
                              hipStream_t stream) {
  const float* x      = (const float*)d_in[0];
  const int*   ei     = (const int*)d_in[1];
  const float* lin1_w = (const float*)d_in[2];
  const float* lin1_b = (const float*)d_in[3];
  const float* nn1_w1 = (const float*)d_in[4];
  const float* nn1_b1 = (const float*)d_in[5];
  const float* nn1_w2 = (const float*)d_in[6];
  const float* nn1_b2 = (const float*)d_in[7];
  const float* bn1_g  = (const float*)d_in[8];
  const float* bn1_b  = (const float*)d_in[9];
  const float* nn2_w1 = (const float*)d_in[10];
  const float* nn2_b1 = (const float*)d_in[11];
  const float* nn2_w2 = (const float*)d_in[12];
  const float* nn2_b2 = (const float*)d_in[13];
  const float* bn2_g  = (const float*)d_in[14];
  const float* bn2_b  = (const float*)d_in[15];
  const float* fc1_w  = (const float*)d_in[16];
  const float* fc1_b  = (const float*)d_in[17];
  const float* fc2_w  = (const float*)d_in[18];
  const float* fc2_b  = (const float*)d_in[19];
  float* out = (float*)d_out;

  float* ws = (float*)d_ws;
  size_t nd = (size_t)NN * DD;
  float* A      = ws;            // g2b (bf16, half the slot)
  float* B      = ws + nd;       // g1b (bf16, half the slot)
  float* cvec   = ws + 2 * nd;
  float* stats1 = cvec + 32;
  float* stats2 = stats1 + 64;
  unsigned short* Bh = (unsigned short*)(stats2 + 64);      // 19456 shorts (38 KB)
  int*   rsA      = (int*)(Bh + KSTEPS * 2 * 64 * 8);       // NN
  int*   reA      = rsA + NN;                               // NN
  int*   srcidx   = reA + NN;                               // NB*BST
  int*   tsrc     = srcidx + (size_t)NB * BST;              // NB*BST ints; dead after kb_fine
  unsigned char* tdst = (unsigned char*)(tsrc + (size_t)NB * BST);  // NB*BST bytes
  int*   bcursor  = (int*)(tdst + (size_t)NB * BST);        // NB
  unsigned short* zb  = (unsigned short*)tsrc;              // aliases dead tsrc (7.2MB >= 6.4MB)
  unsigned short* g1b = (unsigned short*)B;
  unsigned short* g2b = (unsigned short*)A;

  hipMemsetAsync(bcursor, 0, NB * sizeof(int), stream);
  // scatter (blocks 0..SCB-1) + weight prep (blocks SCB..SCB+K0B-1) in one launch
  k0s<<<SCB + K0B, 256, 0, stream>>>(ei, bcursor, tsrc, tdst,
                                     lin1_w, lin1_b, nn1_w1, Bh, cvec, stats1, stats2);
  kb_fine<<<NB, 256, 0, stream>>>(bcursor, tsrc, tdst, rsA, reA, srcidx);
  k1_mfma<<<NN / 32, 256, 0, stream>>>(x, Bh, cvec, zb);
  k3_fused<<<(NN + 63) / 64, 256, 0, stream>>>(zb, rsA, reA, srcidx,
                                               nn1_w2, nn1_b1, nn1_b2, g1b, stats1);
  k6_fused<<<(NN + 63) / 64, 256, 0, stream>>>(g1b, rsA, reA, srcidx,
                                               stats1, bn1_g, bn1_b,
                                               nn2_w1, nn2_b1, nn2_w2, nn2_b2, g2b, stats2);
  k7_head<<<(NN + 255) / 256, 256, 0, stream>>>(g2b, stats2, bn2_g, bn2_b,
                                                fc1_w, fc1_b, fc2_w, fc2_b, out);
}

// Round 18
// 237.155 us; speedup vs baseline: 1.1995x; 1.0148x over previous
//
#include <hip/hip_runtime.h>
#include <cstdint>

#define NN 100000
#define NE 1600000
#define FI 602
#define DD 32
#define CC 41
#define BN_EPS 1e-5f
#define KSTEPS 19                 // 19*32 = 608 >= 602 (k-padded with zeros)

// single-pass bucketed CSR build (packed: src | dlow<<17)
#define NPB 256                   // nodes per bucket (dst >> 8)
#define NB 391                    // ceil(NN/NPB)
#define BST 4608                  // fixed bucket stride (mean 4096, sigma 64 -> 8-sigma margin)
#define EPT 13                    // edges per thread in scatter
#define SCB 481                   // ceil(NE / (256*EPT))
#define K0B 76                    // ceil(KSTEPS*32*32 / 256)

typedef __attribute__((ext_vector_type(8))) short bf16x8;
typedef __attribute__((ext_vector_type(4))) float f32x4;

__device__ __forceinline__ void atomAdd(float* p, float v) {
#ifdef __HIP_PLATFORM_AMD__
  unsafeAtomicAdd(p, v);
#else
  atomicAdd(p, v);
#endif
}

// round-to-nearest-even f32 -> bf16 bits
__device__ __forceinline__ unsigned short f2b(float f) {
  unsigned u = __float_as_uint(f);
  unsigned r = (u + 0x7fffu + ((u >> 16) & 1u)) >> 16;
  return (unsigned short)r;
}
__device__ __forceinline__ float blo(unsigned u) { return __uint_as_float(u << 16); }
__device__ __forceinline__ float bhi(unsigned u) { return __uint_as_float(u & 0xffff0000u); }

// ---------------- K0S: blocks [0,SCB) = edge scatter (packed) ; blocks [SCB,..) = weight prep
__global__ __launch_bounds__(256) void k0s(
    const int* __restrict__ ei, int* __restrict__ bcursor,
    int* __restrict__ tpack,
    const float* __restrict__ lin1_w, const float* __restrict__ lin1_b,
    const float* __restrict__ nn1_w1,
    unsigned short* __restrict__ Bh, float* __restrict__ cvec,
    float* __restrict__ stats1, float* __restrict__ stats2) {
  __shared__ int cnt[NB];
  __shared__ int wbase[NB];
  const int t = threadIdx.x;
  const int blk = blockIdx.x;
  if (blk < SCB) {
    for (int i = t; i < NB; i += 256) cnt[i] = 0;
    __syncthreads();
    const int base = blk * (256 * EPT);
    int s[EPT], d[EPT];
    #pragma unroll
    for (int i = 0; i < EPT; ++i) {
      int e = base + i * 256 + t;
      if (e < NE) {
        s[i] = ei[e];
        d[i] = ei[NE + e];
        atomicAdd(&cnt[d[i] >> 8], 1);
      } else {
        s[i] = -1; d[i] = -1;
      }
    }
    __syncthreads();
    for (int i = t; i < NB; i += 256) wbase[i] = atomicAdd(&bcursor[i], cnt[i]);
    __syncthreads();
    #pragma unroll
    for (int i = 0; i < EPT; ++i) {
      if (d[i] >= 0) {
        int bk = d[i] >> 8;
        int p = atomicAdd(&wbase[bk], 1);
        tpack[bk * BST + p] = s[i] | ((d[i] & (NPB - 1)) << 17);
      }
    }
  } else {
    int o = (blk - SCB) * 256 + t;
    if (o < KSTEPS * 32 * 32) {
      int k = o >> 5, j = o & 31;
      float sm = 0.f;
      if (k < FI) {
        #pragma unroll 4
        for (int c = 0; c < 2 * DD; ++c) sm = fmaf(lin1_w[k * (2 * DD) + c], nn1_w1[c * DD + j], sm);
      }
      int st = k >> 5, kk = k & 31, g = kk >> 3, jj = kk & 7;
      int h = j >> 4, lane = g * 16 + (j & 15);
      int idx = ((st * 2 + h) * 64 + lane) * 8 + jj;
      Bh[idx] = f2b(sm);
    }
    if (blk == SCB) {
      if (t < DD) {
        float sm = 0.f;
        for (int c = 0; c < 2 * DD; ++c) sm = fmaf(lin1_b[c], nn1_w1[c * DD + t], sm);
        cvec[t] = sm;
      }
      if (t >= 128 && t < 192) stats1[t - 128] = 0.f;
      if (t >= 192) stats2[t - 192] = 0.f;
    }
  }
}

// ---------------- per-bucket fine sort: rs/re + compact srcidx (bucket-strided CSR)
__global__ __launch_bounds__(256) void kb_fine(const int* __restrict__ bcursor,
                                               const int* __restrict__ tpack,
                                               int* __restrict__ rs, int* __restrict__ re,
                                               int* __restrict__ srcidx) {
  __shared__ int deg[NPB];
  __shared__ int cur[NPB];
  __shared__ int woff[4];
  const int b = blockIdx.x, t = threadIdx.x;
  const int beg = b * BST;
  const int end = beg + bcursor[b];
  deg[t] = 0;
  __syncthreads();
  for (int i = beg + t; i < end; i += 256) atomicAdd(&deg[tpack[i] >> 17], 1);
  __syncthreads();
  int v = deg[t];
  int lane = t & 63, wave = t >> 6;
  int inc = v;
  #pragma unroll
  for (int off = 1; off < 64; off <<= 1) {
    int u = __shfl_up(inc, off);
    if (lane >= off) inc += u;
  }
  if (lane == 63) woff[wave] = inc;
  __syncthreads();
  int wadd = 0;
  for (int w = 0; w < wave; ++w) wadd += woff[w];
  int excl = wadd + inc - v;
  int gnode = b * NPB + t;
  if (gnode < NN) {
    rs[gnode] = beg + excl;
    re[gnode] = beg + excl + v;
  }
  cur[t] = beg + excl;
  __syncthreads();
  for (int i = beg + t; i < end; i += 256) {
    int pk = tpack[i];
    int p = atomicAdd(&cur[pk >> 17], 1);
    srcidx[p] = pk & 0x1FFFF;
  }
}

// ---------------- K1 v8 (MFMA, k-split): zb = bf16(x @ M + cvec)
__global__ __launch_bounds__(256) void k1_mfma(
    const float* __restrict__ x,
    const unsigned short* __restrict__ Bh,
    const float* __restrict__ cvec, unsigned short* __restrict__ zb) {
  __shared__ float part[2][64][9];
  const int tid = threadIdx.x;
  const int lane = tid & 63;
  const int w = tid >> 6;
  const int rg = w & 1;
  const int kh = w >> 1;
  const int row0 = blockIdx.x * 32 + rg * 16;
  const int g = lane >> 4;
  const int r = row0 + (lane & 15);
  const float* __restrict__ xr = x + (size_t)r * FI + g * 8;
  f32x4 acc0 = {0.f, 0.f, 0.f, 0.f};
  f32x4 acc1 = {0.f, 0.f, 0.f, 0.f};

  if (kh == 0) {
    float4 a0 = *(const float4*)&xr[0];
    float4 b0 = *(const float4*)&xr[4];
    float4 a1 = *(const float4*)&xr[32];
    float4 b1 = *(const float4*)&xr[36];
    bf16x8 f0c = *(const bf16x8*)&Bh[(size_t)lane * 8];
    bf16x8 f1c = *(const bf16x8*)&Bh[(size_t)lane * 8 + 512];
    #pragma unroll
    for (int s = 0; s < 10; ++s) {
      float4 ca = a0, cb = b0;
      a0 = a1; b0 = b1;
      if (s + 2 < 10) {
        a1 = *(const float4*)&xr[(s + 2) * 32];
        b1 = *(const float4*)&xr[(s + 2) * 32 + 4];
      }
      bf16x8 f0n, f1n;
      if (s + 1 < 10) {
        const size_t fb = ((size_t)((s + 1) * 2) * 64 + lane) * 8;
        f0n = *(const bf16x8*)&Bh[fb];
        f1n = *(const bf16x8*)&Bh[fb + 512];
      }
      bf16x8 ahi, alo;
      float cv0[8] = {ca.x, ca.y, ca.z, ca.w, cb.x, cb.y, cb.z, cb.w};
      #pragma unroll
      for (int j = 0; j < 8; ++j) {
        unsigned ub = __float_as_uint(cv0[j]);
        unsigned short h = (unsigned short)(ub >> 16);
        float hv = __uint_as_float(ub & 0xffff0000u);
        float d = cv0[j] - hv;
        ahi[j] = (short)h;
        alo[j] = (short)(__float_as_uint(d) >> 16);
      }
      acc0 = __builtin_amdgcn_mfma_f32_16x16x32_bf16(ahi, f0c, acc0, 0, 0, 0);
      acc1 = __builtin_amdgcn_mfma_f32_16x16x32_bf16(ahi, f1c, acc1, 0, 0, 0);
      acc0 = __builtin_amdgcn_mfma_f32_16x16x32_bf16(alo, f0c, acc0, 0, 0, 0);
      acc1 = __builtin_amdgcn_mfma_f32_16x16x32_bf16(alo, f1c, acc1, 0, 0, 0);
      if (s + 1 < 10) { f0c = f0n; f1c = f1n; }
    }
  } else {
    float4 a0 = *(const float4*)&xr[10 * 32];
    float4 b0 = *(const float4*)&xr[10 * 32 + 4];
    float4 a1 = *(const float4*)&xr[11 * 32];
    float4 b1 = *(const float4*)&xr[11 * 32 + 4];
    bf16x8 f0c = *(const bf16x8*)&Bh[((size_t)(10 * 2) * 64 + lane) * 8];
    bf16x8 f1c = *(const bf16x8*)&Bh[((size_t)(10 * 2) * 64 + lane) * 8 + 512];
    #pragma unroll
    for (int s = 10; s < KSTEPS; ++s) {
      float4 ca = a0, cb = b0;
      a0 = a1; b0 = b1;
      if (s + 2 < KSTEPS - 1) {
        a1 = *(const float4*)&xr[(s + 2) * 32];
        b1 = *(const float4*)&xr[(s + 2) * 32 + 4];
      } else if (s + 2 == KSTEPS - 1) {
        if (g == 3) {
          float2 tt = *(const float2*)&xr[18 * 32];   // cols 600,601
          a1 = make_float4(tt.x, tt.y, 0.f, 0.f);
          b1 = make_float4(0.f, 0.f, 0.f, 0.f);
        } else {
          a1 = *(const float4*)&xr[18 * 32];
          b1 = *(const float4*)&xr[18 * 32 + 4];
        }
      }
      bf16x8 f0n, f1n;
      if (s + 1 < KSTEPS) {
        const size_t fb = ((size_t)((s + 1) * 2) * 64 + lane) * 8;
        f0n = *(const bf16x8*)&Bh[fb];
        f1n = *(const bf16x8*)&Bh[fb + 512];
      }
      bf16x8 ahi, alo;
      float cv0[8] = {ca.x, ca.y, ca.z, ca.w, cb.x, cb.y, cb.z, cb.w};
      #pragma unroll
      for (int j = 0; j < 8; ++j) {
        unsigned ub = __float_as_uint(cv0[j]);
        unsigned short h = (unsigned short)(ub >> 16);
        float hv = __uint_as_float(ub & 0xffff0000u);
        float d = cv0[j] - hv;
        ahi[j] = (short)h;
        alo[j] = (short)(__float_as_uint(d) >> 16);
      }
      acc0 = __builtin_amdgcn_mfma_f32_16x16x32_bf16(ahi, f0c, acc0, 0, 0, 0);
      acc1 = __builtin_amdgcn_mfma_f32_16x16x32_bf16(ahi, f1c, acc1, 0, 0, 0);
      acc0 = __builtin_amdgcn_mfma_f32_16x16x32_bf16(alo, f0c, acc0, 0, 0, 0);
      acc1 = __builtin_amdgcn_mfma_f32_16x16x32_bf16(alo, f1c, acc1, 0, 0, 0);
      if (s + 1 < KSTEPS) { f0c = f0n; f1c = f1n; }
    }
    #pragma unroll
    for (int j = 0; j < 4; ++j) {
      part[rg][lane][j] = acc0[j];
      part[rg][lane][4 + j] = acc1[j];
    }
  }
  __syncthreads();
  if (kh == 0) {
    const int c0 = lane & 15;
    const float cva = cvec[c0], cvb = cvec[16 + c0];
    #pragma unroll
    for (int j = 0; j < 4; ++j) {
      float v0 = acc0[j] + part[rg][lane][j] + cva;
      float v1 = acc1[j] + part[rg][lane][4 + j] + cvb;
      int rr = row0 + g * 4 + j;
      zb[(size_t)rr * DD + c0] = f2b(v0);
      zb[(size_t)rr * DD + 16 + c0] = f2b(v1);
    }
  }
}

// ---------------- gather helper (register, 4 lanes/node, depth-12)
__device__ __forceinline__ void gather12(const unsigned short* __restrict__ srcb,
                                         const int* __restrict__ srcidx,
                                         int beg, int end, int q, float* a) {
  int i = beg;
  for (; i + 12 <= end; i += 12) {
    uint4 v[12];
    #pragma unroll
    for (int j = 0; j < 12; ++j) v[j] = *(const uint4*)&srcb[(size_t)srcidx[i + j] * DD + q * 8];
    #pragma unroll
    for (int j = 0; j < 12; ++j) {
      a[0] += blo(v[j].x); a[1] += bhi(v[j].x);
      a[2] += blo(v[j].y); a[3] += bhi(v[j].y);
      a[4] += blo(v[j].z); a[5] += bhi(v[j].z);
      a[6] += blo(v[j].w); a[7] += bhi(v[j].w);
    }
  }
  for (; i + 4 <= end; i += 4) {
    uint4 v[4];
    #pragma unroll
    for (int j = 0; j < 4; ++j) v[j] = *(const uint4*)&srcb[(size_t)srcidx[i + j] * DD + q * 8];
    #pragma unroll
    for (int j = 0; j < 4; ++j) {
      a[0] += blo(v[j].x); a[1] += bhi(v[j].x);
      a[2] += blo(v[j].y); a[3] += bhi(v[j].y);
      a[4] += blo(v[j].z); a[5] += bhi(v[j].z);
      a[6] += blo(v[j].w); a[7] += bhi(v[j].w);
    }
  }
  for (; i < end; ++i) {
    uint4 v0 = *(const uint4*)&srcb[(size_t)srcidx[i] * DD + q * 8];
    a[0] += blo(v0.x); a[1] += bhi(v0.x);
    a[2] += blo(v0.y); a[3] += bhi(v0.y);
    a[4] += blo(v0.z); a[5] += bhi(v0.z);
    a[6] += blo(v0.w); a[7] += bhi(v0.w);
  }
}

// ---------------- K3 fused (barrier-free after gather): g1b = bf16(mlp1(zb_self + sum zb_nbrs)) ; stats
__global__ __launch_bounds__(256) void k3_fused(
    const unsigned short* __restrict__ zb,
    const int* __restrict__ rsA, const int* __restrict__ reA,
    const int* __restrict__ srcidx,
    const float* __restrict__ w2, const float* __restrict__ b1, const float* __restrict__ b2,
    unsigned short* __restrict__ g1b, float* __restrict__ stats) {
  __shared__ float w2s[DD * DD];
  __shared__ float b1s[DD], b2s[DD];
  __shared__ float ps[4][2 * DD];
  const int tid = threadIdx.x;
  const int lane = tid & 63;
  const int q = tid & 3;
  const int n = blockIdx.x * 64 + (tid >> 2);
  const bool valid = n < NN;
  for (int i = tid; i < DD * DD; i += 256) w2s[i] = w2[i];
  if (tid < DD) b1s[tid] = b1[tid];
  else if (tid < 2 * DD) b2s[tid - DD] = b2[tid - DD];
  __syncthreads();

  float a[8] = {};
  if (valid) {
    uint4 v = *(const uint4*)&zb[(size_t)n * DD + q * 8];
    a[0] = blo(v.x); a[1] = bhi(v.x); a[2] = blo(v.y); a[3] = bhi(v.y);
    a[4] = blo(v.z); a[5] = bhi(v.z); a[6] = blo(v.w); a[7] = bhi(v.w);
    gather12(zb, srcidx, rsA[n], reA[n], q, a);
  }
  float g[8];
  #pragma unroll
  for (int j = 0; j < 8; ++j) g[j] = b2s[q * 8 + j];
  #pragma unroll
  for (int k = 0; k < DD; ++k) {
    float uv = __shfl(a[k & 7], (lane & 0x3c) | (k >> 3), 64);
    float tv = fmaxf(uv + b1s[k], 0.f);
    #pragma unroll
    for (int j = 0; j < 8; ++j) g[j] = fmaf(tv, w2s[k * DD + q * 8 + j], g[j]);
  }
  float sv[8], sq[8];
  #pragma unroll
  for (int j = 0; j < 8; ++j) { sv[j] = valid ? g[j] : 0.f; sq[j] = sv[j] * sv[j]; }
  #pragma unroll
  for (int j = 0; j < 8; ++j) {
    #pragma unroll
    for (int off = 4; off < 64; off <<= 1) { sv[j] += __shfl_xor(sv[j], off); sq[j] += __shfl_xor(sq[j], off); }
  }
  if (lane < 4) {
    int w = tid >> 6;
    #pragma unroll
    for (int j = 0; j < 8; ++j) { ps[w][q * 8 + j] = sv[j]; ps[w][DD + q * 8 + j] = sq[j]; }
  }
  if (valid) {
    unsigned u0 = ((unsigned)f2b(g[1]) << 16) | f2b(g[0]);
    unsigned u1 = ((unsigned)f2b(g[3]) << 16) | f2b(g[2]);
    unsigned u2 = ((unsigned)f2b(g[5]) << 16) | f2b(g[4]);
    unsigned u3 = ((unsigned)f2b(g[7]) << 16) | f2b(g[6]);
    *(uint4*)&g1b[(size_t)n * DD + q * 8] = make_uint4(u0, u1, u2, u3);
  }
  __syncthreads();
  if (tid < 2 * DD)
    atomAdd(&stats[tid], ps[0][tid] + ps[1][tid] + ps[2][tid] + ps[3][tid]);
}

// ---------------- K6 fused: BN1 inline ; u = (self+sum)*rs + (1+deg)*sh ; g2b = bf16(mlp2(u)) ; stats2
__global__ __launch_bounds__(256) void k6_fused(
    const unsigned short* __restrict__ g1b,
    const int* __restrict__ rsA, const int* __restrict__ reA,
    const int* __restrict__ srcidx,
    const float* __restrict__ stats1, const float* __restrict__ bn1_g, const float* __restrict__ bn1_b,
    const float* __restrict__ w1, const float* __restrict__ b1,
    const float* __restrict__ w2, const float* __restrict__ b2,
    unsigned short* __restrict__ g2b, float* __restrict__ stats) {
  __shared__ float w1s[DD * DD];
  __shared__ float w2s[DD * DD];
  __shared__ float bns[2 * DD];
  __shared__ float b1s[DD], b2s[DD];
  __shared__ float ps[4][2 * DD];
  const int tid = threadIdx.x;
  const int lane = tid & 63;
  const int q = tid & 3;
  const int n = blockIdx.x * 64 + (tid >> 2);
  const bool valid = n < NN;
  for (int i = tid; i < DD * DD; i += 256) { w1s[i] = w1[i]; w2s[i] = w2[i]; }
  if (tid < DD) {
    float mu = stats1[tid] * (1.f / NN);
    float var = stats1[DD + tid] * (1.f / NN) - mu * mu;
    float rsv = rsqrtf(var + BN_EPS) * bn1_g[tid];
    bns[tid] = rsv;
    bns[DD + tid] = bn1_b[tid] - mu * rsv;
    b1s[tid] = b1[tid];
  } else if (tid < 2 * DD) {
    b2s[tid - DD] = b2[tid - DD];
  }
  __syncthreads();

  float a[8] = {};
  float degp1 = 1.f;
  if (valid) {
    uint4 v = *(const uint4*)&g1b[(size_t)n * DD + q * 8];
    a[0] = blo(v.x); a[1] = bhi(v.x); a[2] = blo(v.y); a[3] = bhi(v.y);
    a[4] = blo(v.z); a[5] = bhi(v.z); a[6] = blo(v.w); a[7] = bhi(v.w);
    int beg = rsA[n], end = reA[n];
    degp1 = (float)(end - beg + 1);
    gather12(g1b, srcidx, beg, end, q, a);
  }
  float t1[8];
  #pragma unroll
  for (int j = 0; j < 8; ++j) t1[j] = b1s[q * 8 + j];
  #pragma unroll
  for (int k = 0; k < DD; ++k) {
    float uv = __shfl(a[k & 7], (lane & 0x3c) | (k >> 3), 64);
    float u = fmaf(uv, bns[k], degp1 * bns[DD + k]);
    #pragma unroll
    for (int j = 0; j < 8; ++j) t1[j] = fmaf(u, w1s[k * DD + q * 8 + j], t1[j]);
  }
  #pragma unroll
  for (int j = 0; j < 8; ++j) t1[j] = fmaxf(t1[j], 0.f);
  float g[8];
  #pragma unroll
  for (int j = 0; j < 8; ++j) g[j] = b2s[q * 8 + j];
  #pragma unroll
  for (int k = 0; k < DD; ++k) {
    float tv = __shfl(t1[k & 7], (lane & 0x3c) | (k >> 3), 64);
    #pragma unroll
    for (int j = 0; j < 8; ++j) g[j] = fmaf(tv, w2s[k * DD + q * 8 + j], g[j]);
  }
  float sv[8], sq[8];
  #pragma unroll
  for (int j = 0; j < 8; ++j) { sv[j] = valid ? g[j] : 0.f; sq[j] = sv[j] * sv[j]; }
  #pragma unroll
  for (int j = 0; j < 8; ++j) {
    #pragma unroll
    for (int off = 4; off < 64; off <<= 1) { sv[j] += __shfl_xor(sv[j], off); sq[j] += __shfl_xor(sq[j], off); }
  }
  if (lane < 4) {
    int w = tid >> 6;
    #pragma unroll
    for (int j = 0; j < 8; ++j) { ps[w][q * 8 + j] = sv[j]; ps[w][DD + q * 8 + j] = sq[j]; }
  }
  if (valid) {
    unsigned u0 = ((unsigned)f2b(g[1]) << 16) | f2b(g[0]);
    unsigned u1 = ((unsigned)f2b(g[3]) << 16) | f2b(g[2]);
    unsigned u2 = ((unsigned)f2b(g[5]) << 16) | f2b(g[4]);
    unsigned u3 = ((unsigned)f2b(g[7]) << 16) | f2b(g[6]);
    *(uint4*)&g2b[(size_t)n * DD + q * 8] = make_uint4(u0, u1, u2, u3);
  }
  __syncthreads();
  if (tid < 2 * DD)
    atomAdd(&stats[tid], ps[0][tid] + ps[1][tid] + ps[2][tid] + ps[3][tid]);
}

// ---------------- K7 v3: out = relu(bn2(g2b)@fc1+b)@fc2+b
// Uniform control flow (no barrier in divergent branches); per-thread row read;
// output staged in two 21/20-col passes (21 KB LDS).
__global__ __launch_bounds__(256) void k7_head(
    const unsigned short* __restrict__ g2b, const float* __restrict__ stats2,
    const float* __restrict__ bn2_g, const float* __restrict__ bn2_b,
    const float* __restrict__ fc1_w, const float* __restrict__ fc1_b,
    const float* __restrict__ fc2_w, const float* __restrict__ fc2_b,
    float* __restrict__ out) {
  __shared__ float fc1s[DD * DD];
  __shared__ float fc2s[DD * CC];
  __shared__ float mu2[DD], rsg2[DD], bet2[DD];
  __shared__ float buf[256 * 21];
  const int tid = threadIdx.x;
  const int n0 = blockIdx.x * 256;
  const int n = n0 + tid;
  const bool valid = n < NN;
  if (tid < DD) {
    float mu = stats2[tid] * (1.f / NN);
    float var = stats2[DD + tid] * (1.f / NN) - mu * mu;
    mu2[tid] = mu;
    rsg2[tid] = rsqrtf(var + BN_EPS) * bn2_g[tid];
    bet2[tid] = bn2_b[tid];
  }
  for (int i = tid; i < DD * DD; i += 256) fc1s[i] = fc1_w[i];
  for (int i = tid; i < DD * CC; i += 256) fc2s[i] = fc2_w[i];
  __syncthreads();

  // guarded loads; ALL threads execute the same instruction stream below
  unsigned wds[16] = {};
  if (valid) {
    uint4 va = *(const uint4*)&g2b[(size_t)n * DD];
    uint4 vb = *(const uint4*)&g2b[(size_t)n * DD + 8];
    uint4 vc = *(const uint4*)&g2b[(size_t)n * DD + 16];
    uint4 vd = *(const uint4*)&g2b[(size_t)n * DD + 24];
    wds[0] = va.x;  wds[1] = va.y;  wds[2] = va.z;  wds[3] = va.w;
    wds[4] = vb.x;  wds[5] = vb.y;  wds[6] = vb.z;  wds[7] = vb.w;
    wds[8] = vc.x;  wds[9] = vc.y;  wds[10] = vc.z; wds[11] = vc.w;
    wds[12] = vd.x; wds[13] = vd.y; wds[14] = vd.z; wds[15] = vd.w;
  }
  float t[DD];
  #pragma unroll
  for (int j = 0; j < DD; ++j) t[j] = fc1_b[j];
  #pragma unroll
  for (int k = 0; k < DD; ++k) {
    float raw = (k & 1) ? bhi(wds[k >> 1]) : blo(wds[k >> 1]);
    float uv = (raw - mu2[k]) * rsg2[k] + bet2[k];
    #pragma unroll
    for (int j = 0; j < DD; ++j) t[j] = fmaf(uv, fc1s[k * DD + j], t[j]);
  }
  #pragma unroll
  for (int j = 0; j < DD; ++j) t[j] = fmaxf(t[j], 0.f);
  float o[CC];
  #pragma unroll
  for (int j = 0; j < CC; ++j) o[j] = fc2_b[j];
  #pragma unroll
  for (int k = 0; k < DD; ++k) {
    float tv = t[k];
    #pragma unroll
    for (int j = 0; j < CC; ++j) o[j] = fmaf(tv, fc2s[k * CC + j], o[j]);
  }
  // pass 1: cols 0..20 (all threads write buf; invalid rows never read back)
  #pragma unroll
  for (int j = 0; j < 21; ++j) buf[tid * 21 + j] = o[j];
  __syncthreads();
  #pragma unroll
  for (int i = 0; i < 21; ++i) {
    int l = tid + i * 256;
    int r = l / 21, c = l % 21;
    if (n0 + r < NN) out[(size_t)(n0 + r) * CC + c] = buf[r * 21 + c];
  }
  __syncthreads();
  // pass 2: cols 21..40
  #pragma unroll
  for (int j = 0; j < 20; ++j) buf[tid * 20 + j] = o[21 + j];
  __syncthreads();
  #pragma unroll
  for (int i = 0; i < 20; ++i) {
    int l = tid + i * 256;
    int r = l / 20, c = l % 20;
    if (n0 + r < NN) out[(size_t)(n0 + r) * CC + 21 + c] = buf[r * 20 + c];
  }
}

extern "C" void kernel_launch(void* const* d_in, const int* in_sizes, int n_in,
                              void* d_out, int out_size, void* d_ws, size_t ws_size,
                              hipStream_t stream) {
  const float* x      = (const float*)d_in[0];
  const int*   ei     = (const int*)d_in[1];
  const float* lin1_w = (const float*)d_in[2];
  const float* lin1_b = (const float*)d_in[3];
  const float* nn1_w1 = (const float*)d_in[4];
  const float* nn1_b1 = (const float*)d_in[5];
  const float* nn1_w2 = (const float*)d_in[6];
  const float* nn1_b2 = (const float*)d_in[7];
  const float* bn1_g  = (const float*)d_in[8];
  const float* bn1_b  = (const float*)d_in[9];
  const float* nn2_w1 = (const float*)d_in[10];
  const float* nn2_b1 = (const float*)d_in[11];
  const float* nn2_w2 = (const float*)d_in[12];
  const float* nn2_b2 = (const float*)d_in[13];
  const float* bn2_g  = (const float*)d_in[14];
  const float* bn2_b  = (const float*)d_in[15];
  const float* fc1_w  = (const float*)d_in[16];
  const float* fc1_b  = (const float*)d_in[17];
  const float* fc2_w  = (const float*)d_in[18];
  const float* fc2_b  = (const float*)d_in[19];
  float* out = (float*)d_out;

  float* ws = (float*)d_ws;
  size_t nd = (size_t)NN * DD;
  float* A      = ws;            // g2b (bf16, half the slot)
  float* B      = ws + nd;       // g1b (bf16, half the slot)
  float* cvec   = ws + 2 * nd;
  float* stats1 = cvec + 32;
  float* stats2 = stats1 + 64;
  unsigned short* Bh = (unsigned short*)(stats2 + 64);      // 19456 shorts (38 KB)
  int*   rsA      = (int*)(Bh + KSTEPS * 2 * 64 * 8);       // NN
  int*   reA      = rsA + NN;                               // NN
  int*   srcidx   = reA + NN;                               // NB*BST
  int*   tpack    = srcidx + (size_t)NB * BST;              // NB*BST ints; dead after kb_fine
  int*   bcursor  = tpack + (size_t)NB * BST;               // NB
  unsigned short* zb  = (unsigned short*)tpack;             // aliases dead tpack (7.2MB >= 6.4MB)
  unsigned short* g1b = (unsigned short*)B;
  unsigned short* g2b = (unsigned short*)A;

  hipMemsetAsync(bcursor, 0, NB * sizeof(int), stream);
  k0s<<<SCB + K0B, 256, 0, stream>>>(ei, bcursor, tpack,
                                     lin1_w, lin1_b, nn1_w1, Bh, cvec, stats1, stats2);
  kb_fine<<<NB, 256, 0, stream>>>(bcursor, tpack, rsA, reA, srcidx);
  k1_mfma<<<NN / 32, 256, 0, stream>>>(x, Bh, cvec, zb);
  k3_fused<<<(NN + 63) / 64, 256, 0, stream>>>(zb, rsA, reA, srcidx,
                                               nn1_w2, nn1_b1, nn1_b2, g1b, stats1);
  k6_fused<<<(NN + 63) / 64, 256, 0, stream>>>(g1b, rsA, reA, srcidx,
                                               stats1, bn1_g, bn1_b,
                                               nn2_w1, nn2_b1, nn2_w2, nn2_b2, g2b, stats2);
  k7_head<<<(NN + 255) / 256, 256, 0, stream>>>(g2b, stats2, bn2_g, bn2_b,
                                                fc1_w, fc1_b, fc2_w, fc2_b, out);
}